// Round 2
// baseline (3088.240 us; speedup 1.0000x reference)
//
#include <hip/hip_runtime.h>

typedef unsigned short u16;
typedef unsigned int   u32;
typedef __attribute__((ext_vector_type(8))) __bf16 bf16x8;
typedef __attribute__((ext_vector_type(4))) float  f32x4;
typedef __attribute__((ext_vector_type(8))) short  short8;
typedef __attribute__((ext_vector_type(4))) double dbl4;

#define NSLOT_ 16384   // N * K = 8192 * 2

__device__ __forceinline__ u16 f2bf(float f){
  u32 u = __float_as_uint(f);
  u32 lsb = (u >> 16) & 1u;
  u += 0x7fffu + lsb;
  return (u16)(u >> 16);
}

__device__ __forceinline__ void gl_lds16(const void* gptr, void* lptr){
  __builtin_amdgcn_global_load_lds((const __attribute__((address_space(1))) u32*)gptr,
                                   (__attribute__((address_space(3))) u32*)lptr, 16, 0, 0);
}

// ---------------- per-token LayerNorm over D=512, f64, writes h64 ----------------
__global__ __launch_bounds__(256) void ln_kernel(const float* __restrict__ x,
    const float* __restrict__ g, const float* __restrict__ bb, double* __restrict__ h64){
  int n = blockIdx.x, t = threadIdx.x;
  const float* xr = x + ((size_t)n << 9);
  float2 v = *(const float2*)&xr[t*2];
  double vx = v.x, vy = v.y;
  double s = vx + vy;
  double q = vx*vx + vy*vy;
  #pragma unroll
  for (int o = 32; o > 0; o >>= 1){ s += __shfl_down(s, o, 64); q += __shfl_down(q, o, 64); }
  __shared__ double ls[4], lq_[4];
  __shared__ double sm, sv;
  int wid = t >> 6, lane = t & 63;
  if (lane == 0){ ls[wid] = s; lq_[wid] = q; }
  __syncthreads();
  if (t == 0){
    double S = ls[0]+ls[1]+ls[2]+ls[3], Q = lq_[0]+lq_[1]+lq_[2]+lq_[3];
    double mean = S * (1.0/512.0);
    double var  = Q * (1.0/512.0) - mean*mean;
    sm = mean; sv = 1.0/sqrt(var + 1e-5);
  }
  __syncthreads();
  double mean = sm, inv = sv;
  int d = t*2;
  double ox = (vx - mean)*inv*(double)g[d]   + (double)bb[d];
  double oy = (vy - mean)*inv*(double)g[d+1] + (double)bb[d+1];
  double2 o; o.x = ox; o.y = oy;
  *(double2*)&h64[((size_t)n<<9) + d] = o;
}

// ---------------- column stats over T per (b,d), f64 ----------------
__global__ __launch_bounds__(256) void colstats(const double* __restrict__ h64,
    double* __restrict__ cs, double* __restrict__ cq){
  int bid = blockIdx.x;
  int b = bid >> 3, ch = bid & 7;
  int t = threadIdx.x;
  int col = ch*64 + (t & 63);
  int tp = t >> 6;
  const double* base = h64 + ((size_t)b << 19);
  double s = 0.0, q = 0.0;
  for (int tt = tp; tt < 1024; tt += 4){
    double v = base[((size_t)tt << 9) + col];
    s += v; q += v*v;
  }
  __shared__ double ls[4][64], lq[4][64];
  ls[tp][t & 63] = s; lq[tp][t & 63] = q;
  __syncthreads();
  if (tp == 0){
    double S = ls[0][t]+ls[1][t]+ls[2][t]+ls[3][t];
    double Q = lq[0][t]+lq[1][t]+lq[2][t]+lq[3][t];
    cs[(b<<9)+col] = S; cq[(b<<9)+col] = Q;
  }
}

// ---------------- subject MLP -> per-(b,d) affine a,c (f64) ----------------
__global__ __launch_bounds__(256) void subj_kernel(const int* __restrict__ sid,
    const float* __restrict__ semb,
    const float* __restrict__ h1w, const float* __restrict__ h1b,
    const float* __restrict__ h2w, const float* __restrict__ h2b,
    const float* __restrict__ s1w, const float* __restrict__ s1b,
    const float* __restrict__ s2w, const float* __restrict__ s2b,
    const double* __restrict__ cs, const double* __restrict__ cq,
    double* __restrict__ a64, double* __restrict__ c64, int l){
  __shared__ double ev[64], hid1[128], hh[128], sh[64], sp[1024];
  int t = threadIdx.x;
  for (int b = 0; b < 8; ++b){
    int s = sid[b];
    if (t < 64) ev[t] = (double)semb[l*4096 + s*64 + t];
    __syncthreads();
    if (t < 128){
      double acc = (double)h1b[l*128 + t];
      for (int i = 0; i < 64; ++i) acc += ev[i]*(double)h1w[l*8192 + i*128 + t];
      hid1[t] = acc > 0.0 ? acc : 0.0;
    }
    __syncthreads();
    if (t < 128){
      double acc = (double)h2b[l*128 + t];
      for (int i = 0; i < 128; ++i) acc += hid1[i]*(double)h2w[l*16384 + i*128 + t];
      hh[t] = acc;
    }
    __syncthreads();
    if (t < 64){
      double acc = (double)s1b[l*64 + t];
      for (int i = 0; i < 128; ++i) acc += hh[i]*(double)s1w[l*8192 + i*64 + t];
      sh[t] = acc > 0.0 ? acc : 0.0;
    }
    __syncthreads();
    for (int m = t; m < 1024; m += 256){
      double acc = (double)s2b[l*1024 + m];
      for (int j = 0; j < 64; ++j) acc += sh[j]*(double)s2w[l*65536 + j*1024 + m];
      sp[m] = acc;
    }
    __syncthreads();
    for (int d = t; d < 512; d += 256){
      double mu  = cs[(b<<9)+d] * (1.0/1024.0);
      double var = cq[(b<<9)+d] * (1.0/1024.0) - mu*mu;
      double inv = 1.0/sqrt(var + 1e-8);
      double spv = sp[d];
      double gamma = (spv > 30.0 ? spv : log1p(exp(spv))) + 1e-8;
      double beta  = sp[512 + d];
      double A = gamma * inv;
      a64[(b<<9)+d] = A;
      c64[(b<<9)+d] = beta - mu*A;
    }
    __syncthreads();
  }
}

// ---------------- hf = h*a + c  -> f32 and bf16 ----------------
__global__ __launch_bounds__(256) void hfcast(const double* __restrict__ h64,
    const double* __restrict__ a64, const double* __restrict__ c64,
    float* __restrict__ hf32, u16* __restrict__ hfb){
  size_t i0 = ((size_t)blockIdx.x*256 + threadIdx.x) * 8;
  int n = (int)(i0 >> 9);
  int d0 = (int)(i0 & 511);
  int b = n >> 10;
  dbl4 x0 = *(const dbl4*)&h64[i0];
  dbl4 x1 = *(const dbl4*)&h64[i0 + 4];
  dbl4 a0 = *(const dbl4*)&a64[(b<<9) + d0];
  dbl4 a1 = *(const dbl4*)&a64[(b<<9) + d0 + 4];
  dbl4 c0 = *(const dbl4*)&c64[(b<<9) + d0];
  dbl4 c1 = *(const dbl4*)&c64[(b<<9) + d0 + 4];
  float f[8];
  #pragma unroll
  for (int j = 0; j < 4; ++j) f[j]   = (float)(x0[j]*a0[j] + c0[j]);
  #pragma unroll
  for (int j = 0; j < 4; ++j) f[4+j] = (float)(x1[j]*a1[j] + c1[j]);
  float4 o0, o1;
  o0.x=f[0]; o0.y=f[1]; o0.z=f[2]; o0.w=f[3];
  o1.x=f[4]; o1.y=f[5]; o1.z=f[6]; o1.w=f[7];
  *(float4*)&hf32[i0]   = o0;
  *(float4*)&hf32[i0+4] = o1;
  short8 ob;
  #pragma unroll
  for (int j = 0; j < 8; ++j) ob[j] = (short)f2bf(f[j]);
  *(short8*)&hfb[i0] = ob;
}

__global__ void zero_counts(int* __restrict__ counts){
  if (threadIdx.x < 8) counts[threadIdx.x] = 0;
}

// ---------------- gating: full f64, top-2 ----------------
__global__ __launch_bounds__(256) void gate_kernel(const double* __restrict__ h64,
    const double* __restrict__ a64, const double* __restrict__ c64,
    const float* __restrict__ g1w, const float* __restrict__ g1b,
    const float* __restrict__ g2w, const float* __restrict__ g2b,
    int* __restrict__ idxo, float* __restrict__ wo_, int* __restrict__ counts){
  __shared__ double hfT[64*32];                 // 16 KB  [k][token]
  __shared__ __align__(16) double ovl[8192];    // 64 KB: g1s (f32) then hid_s (f64)
  __shared__ double lg[32*8];
  __shared__ int lcnt[8];
  float*  g1s   = (float*)ovl;
  double* hid_s = ovl;
  int t = threadIdx.x;
  int tok0 = blockIdx.x << 5;
  int b = tok0 >> 10;
  if (t < 8) lcnt[t] = 0;
  double acc[32];
  #pragma unroll
  for (int i = 0; i < 32; ++i) acc[i] = 0.0;
  int r_st = t & 31, kp_st = t >> 5;
  int tokr = (t >> 6) << 3, col0 = (t & 63) << 2;
  for (int kc = 0; kc < 512; kc += 64){
    {
      int dbase = kc + (kp_st << 3);
      const double* hrow = h64 + (((size_t)(tok0 + r_st)) << 9) + dbase;
      dbl4 x0 = *(const dbl4*)hrow;
      dbl4 x1 = *(const dbl4*)(hrow + 4);
      dbl4 a0 = *(const dbl4*)&a64[(b<<9) + dbase];
      dbl4 a1 = *(const dbl4*)&a64[(b<<9) + dbase + 4];
      dbl4 c0 = *(const dbl4*)&c64[(b<<9) + dbase];
      dbl4 c1 = *(const dbl4*)&c64[(b<<9) + dbase + 4];
      #pragma unroll
      for (int u = 0; u < 4; ++u) hfT[((kp_st<<3)+u)*32 + r_st]   = x0[u]*a0[u] + c0[u];
      #pragma unroll
      for (int u = 0; u < 4; ++u) hfT[((kp_st<<3)+4+u)*32 + r_st] = x1[u]*a1[u] + c1[u];
    }
    #pragma unroll
    for (int i = 0; i < 16; ++i){
      int f4 = (i << 8) + t;
      int row = f4 >> 6, c4 = (f4 & 63) << 2;
      *(float4*)&g1s[(row << 8) + c4] = *(const float4*)&g1w[((size_t)(kc+row) << 8) + c4];
    }
    __syncthreads();
    for (int kk = 0; kk < 64; ++kk){
      float4 gv = *(const float4*)&g1s[(kk << 8) + col0];
      double g0 = gv.x, g1 = gv.y, g2 = gv.z, g3 = gv.w;
      const double* hp = &hfT[(kk << 5) + tokr];
      #pragma unroll
      for (int tr = 0; tr < 8; ++tr){
        double hv = hp[tr];
        acc[tr*4+0] = fma(hv, g0, acc[tr*4+0]);
        acc[tr*4+1] = fma(hv, g1, acc[tr*4+1]);
        acc[tr*4+2] = fma(hv, g2, acc[tr*4+2]);
        acc[tr*4+3] = fma(hv, g3, acc[tr*4+3]);
      }
    }
    __syncthreads();
  }
  // hid_s overlays g1s (all g1s reads are behind the barrier above)
  #pragma unroll
  for (int tr = 0; tr < 8; ++tr){
    #pragma unroll
    for (int cc = 0; cc < 4; ++cc){
      double v = acc[tr*4+cc] + (double)g1b[col0+cc];
      hid_s[(tokr+tr)*256 + col0 + cc] = v > 0.0 ? v : 0.0;
    }
  }
  __syncthreads();
  {
    int tok = t >> 3, e = t & 7;
    double la = (double)g2b[e];
    for (int k = 0; k < 256; ++k) la += hid_s[(tok<<8)+k]*(double)g2w[(k<<3)+e];
    lg[(tok<<3)+e] = la;
  }
  __syncthreads();
  if (t < 32){
    double l0[8];
    #pragma unroll
    for (int e = 0; e < 8; ++e) l0[e] = lg[(t<<3)+e];
    double m = l0[0];
    #pragma unroll
    for (int e = 1; e < 8; ++e) m = fmax(m, l0[e]);
    double p[8]; double s = 0.0;
    #pragma unroll
    for (int e = 0; e < 8; ++e){ p[e] = exp(l0[e]-m); s += p[e]; }
    double b1 = -1e300, b2 = -1e300; int i1 = 0, i2 = 1;
    #pragma unroll
    for (int e = 0; e < 8; ++e){
      double v = l0[e];
      if (v > b1){ b2 = b1; i2 = i1; b1 = v; i1 = e; }
      else if (v > b2){ b2 = v; i2 = e; }
    }
    double pr1 = p[i1]/s, pr2 = p[i2]/s;
    double den = pr1 + pr2 + 1e-8;
    int n = tok0 + t;
    idxo[2*n] = i1; idxo[2*n+1] = i2;
    wo_[2*n] = (float)(pr1/den); wo_[2*n+1] = (float)(pr2/den);
    atomicAdd(&lcnt[i1], 1); atomicAdd(&lcnt[i2], 1);
  }
  __syncthreads();
  if (t < 8) atomicAdd(&counts[t], lcnt[t]);
}

__global__ void offsets_kernel(const int* __restrict__ counts, int* __restrict__ offs,
                               int* __restrict__ cur){
  if (threadIdx.x == 0 && blockIdx.x == 0){
    int run = 0;
    for (int e = 0; e < 8; ++e){ offs[e] = run; run += counts[e]; cur[e] = 0; }
  }
}

// ---------------- scatter tokens into compacted per-expert slot lists ----------------
__global__ __launch_bounds__(256) void scatter_kernel(const int* __restrict__ idx,
    const int* __restrict__ offs, int* __restrict__ cur,
    int* __restrict__ tok_of, int* __restrict__ slot_of){
  __shared__ int lcnt[8], lbase[8];
  int t = threadIdx.x;
  int n = blockIdx.x*256 + t;
  if (t < 8) lcnt[t] = 0;
  __syncthreads();
  int e0 = idx[2*n], e1 = idx[2*n+1];
  int p0 = atomicAdd(&lcnt[e0], 1);
  int p1 = atomicAdd(&lcnt[e1], 1);
  __syncthreads();
  if (t < 8) lbase[t] = atomicAdd(&cur[t], lcnt[t]);
  __syncthreads();
  int s0 = offs[e0] + lbase[e0] + p0;
  int s1 = offs[e1] + lbase[e1] + p1;
  tok_of[s0] = n; tok_of[s1] = n;
  slot_of[2*n] = s0; slot_of[2*n+1] = s1;
}

// ---------------- layer-1 up-GEMM: f32 data, f64 accumulate (vector) ----------------
// grid: e(8) x mt(128, 64 rows each) x nt(32, 32 cols each)
__global__ __launch_bounds__(256) void up1_kernel(const float* __restrict__ hf32,
    const float* __restrict__ wi0, const float* __restrict__ wi1,
    const int* __restrict__ tok_of, const int* __restrict__ offs, const int* __restrict__ counts,
    float* __restrict__ hid32){
  int bx = blockIdx.x;
  int e  = bx >> 12;
  int mt = (bx >> 5) & 127;
  int nt = bx & 31;
  int base = offs[e], cnt = counts[e];
  int row0 = mt << 6;
  if (row0 >= cnt) return;
  __shared__ double hfs[64*65];       // [k][row] padded
  __shared__ double w0s[64*32], w1s[64*32];   // [k][c]
  int t = threadIdx.x;
  int srow = t >> 2;                  // 0..63
  int sk0  = (t & 3) << 4;            // 16 k each
  int ss = base + row0 + srow; ss = ss < NSLOT_ ? ss : NSLOT_-1;
  const float* hrow = hf32 + ((size_t)tok_of[ss] << 9);
  int wk  = t >> 2;                   // 0..63
  int wc0 = (t & 3) << 3;             // 8 cols each
  size_t wb = (size_t)e*524288 + (size_t)(nt*32) + wc0;
  int r  = t & 63;
  int c0 = (t >> 6) << 3;             // 8 cols per thread
  double acc0[8], acc1[8];
  #pragma unroll
  for (int j = 0; j < 8; ++j){ acc0[j] = 0.0; acc1[j] = 0.0; }
  for (int kc = 0; kc < 512; kc += 64){
    {
      float4 hA = *(const float4*)&hrow[kc + sk0];
      float4 hB = *(const float4*)&hrow[kc + sk0 + 4];
      float4 hC = *(const float4*)&hrow[kc + sk0 + 8];
      float4 hD = *(const float4*)&hrow[kc + sk0 + 12];
      hfs[(sk0+0)*65+srow]=hA.x; hfs[(sk0+1)*65+srow]=hA.y; hfs[(sk0+2)*65+srow]=hA.z; hfs[(sk0+3)*65+srow]=hA.w;
      hfs[(sk0+4)*65+srow]=hB.x; hfs[(sk0+5)*65+srow]=hB.y; hfs[(sk0+6)*65+srow]=hB.z; hfs[(sk0+7)*65+srow]=hB.w;
      hfs[(sk0+8)*65+srow]=hC.x; hfs[(sk0+9)*65+srow]=hC.y; hfs[(sk0+10)*65+srow]=hC.z; hfs[(sk0+11)*65+srow]=hC.w;
      hfs[(sk0+12)*65+srow]=hD.x; hfs[(sk0+13)*65+srow]=hD.y; hfs[(sk0+14)*65+srow]=hD.z; hfs[(sk0+15)*65+srow]=hD.w;
      const float* w0p = wi0 + wb + (size_t)(kc + wk)*1024;
      const float* w1p = wi1 + wb + (size_t)(kc + wk)*1024;
      float4 v0 = *(const float4*)&w0p[0];
      float4 v1 = *(const float4*)&w0p[4];
      float4 u0 = *(const float4*)&w1p[0];
      float4 u1 = *(const float4*)&w1p[4];
      double* wd0 = &w0s[wk*32 + wc0];
      double* wd1 = &w1s[wk*32 + wc0];
      wd0[0]=v0.x; wd0[1]=v0.y; wd0[2]=v0.z; wd0[3]=v0.w;
      wd0[4]=v1.x; wd0[5]=v1.y; wd0[6]=v1.z; wd0[7]=v1.w;
      wd1[0]=u0.x; wd1[1]=u0.y; wd1[2]=u0.z; wd1[3]=u0.w;
      wd1[4]=u1.x; wd1[5]=u1.y; wd1[6]=u1.z; wd1[7]=u1.w;
    }
    __syncthreads();
    for (int kk = 0; kk < 64; ++kk){
      double hv = hfs[kk*65 + r];
      const double* wr0 = &w0s[kk*32 + c0];
      const double* wr1 = &w1s[kk*32 + c0];
      #pragma unroll
      for (int j = 0; j < 8; ++j){
        acc0[j] = fma(hv, wr0[j], acc0[j]);
        acc1[j] = fma(hv, wr1[j], acc1[j]);
      }
    }
    __syncthreads();
  }
  int rr = row0 + r;
  if (rr < cnt){
    float* orow = hid32 + ((size_t)(base + rr) << 10) + nt*32 + c0;
    #pragma unroll
    for (int j = 0; j < 8; ++j){
      double u0 = acc0[j] > 0.0 ? acc0[j] : 0.0;
      orow[j] = (float)(u0 * acc1[j]);
    }
  }
}

// ---------------- layer-1 down-GEMM: f32 data, f64 accumulate (vector) ----------------
// grid: e(8) x mt(128, 64 rows) x nt(8, 64 cols)
__global__ __launch_bounds__(256) void down1_kernel(const float* __restrict__ hid32,
    const float* __restrict__ wo, const int* __restrict__ offs, const int* __restrict__ counts,
    float* __restrict__ eo32){
  int bx = blockIdx.x;
  int e  = bx >> 10;
  int mt = (bx >> 3) & 127;
  int nt = bx & 7;
  int base = offs[e], cnt = counts[e];
  int row0 = mt << 6;
  if (row0 >= cnt) return;
  __shared__ double hds[64*65];       // [k][row]
  __shared__ double wos[64*64];       // [k][c]
  int t = threadIdx.x;
  int srow = t >> 2;
  int sk0  = (t & 3) << 4;
  int ss = base + row0 + srow; ss = ss < NSLOT_ ? ss : NSLOT_-1;
  const float* hrow = hid32 + ((size_t)ss << 10);
  int wk  = t >> 2;
  int wc0 = (t & 3) << 4;             // 16 cols each
  size_t wb = (size_t)e*524288 + (size_t)(nt*64) + wc0;
  int r  = t & 63;
  int c0 = (t >> 6) << 4;             // 16 cols per thread
  double acc[16];
  #pragma unroll
  for (int j = 0; j < 16; ++j) acc[j] = 0.0;
  for (int kc = 0; kc < 1024; kc += 64){
    {
      float4 hA = *(const float4*)&hrow[kc + sk0];
      float4 hB = *(const float4*)&hrow[kc + sk0 + 4];
      float4 hC = *(const float4*)&hrow[kc + sk0 + 8];
      float4 hD = *(const float4*)&hrow[kc + sk0 + 12];
      hds[(sk0+0)*65+srow]=hA.x; hds[(sk0+1)*65+srow]=hA.y; hds[(sk0+2)*65+srow]=hA.z; hds[(sk0+3)*65+srow]=hA.w;
      hds[(sk0+4)*65+srow]=hB.x; hds[(sk0+5)*65+srow]=hB.y; hds[(sk0+6)*65+srow]=hB.z; hds[(sk0+7)*65+srow]=hB.w;
      hds[(sk0+8)*65+srow]=hC.x; hds[(sk0+9)*65+srow]=hC.y; hds[(sk0+10)*65+srow]=hC.z; hds[(sk0+11)*65+srow]=hC.w;
      hds[(sk0+12)*65+srow]=hD.x; hds[(sk0+13)*65+srow]=hD.y; hds[(sk0+14)*65+srow]=hD.z; hds[(sk0+15)*65+srow]=hD.w;
      const float* wp = wo + wb + (size_t)(kc + wk)*512;
      float4 v0 = *(const float4*)&wp[0];
      float4 v1 = *(const float4*)&wp[4];
      float4 v2 = *(const float4*)&wp[8];
      float4 v3 = *(const float4*)&wp[12];
      double* wd = &wos[wk*64 + wc0];
      wd[0]=v0.x; wd[1]=v0.y; wd[2]=v0.z; wd[3]=v0.w;
      wd[4]=v1.x; wd[5]=v1.y; wd[6]=v1.z; wd[7]=v1.w;
      wd[8]=v2.x; wd[9]=v2.y; wd[10]=v2.z; wd[11]=v2.w;
      wd[12]=v3.x; wd[13]=v3.y; wd[14]=v3.z; wd[15]=v3.w;
    }
    __syncthreads();
    for (int kk = 0; kk < 64; ++kk){
      double hv = hds[kk*65 + r];
      const double* wr = &wos[kk*64 + c0];
      #pragma unroll
      for (int j = 0; j < 16; ++j) acc[j] = fma(hv, wr[j], acc[j]);
    }
    __syncthreads();
  }
  int rr = row0 + r;
  if (rr < cnt){
    float* orow = eo32 + ((size_t)(base + rr) << 9) + nt*64 + c0;
    #pragma unroll
    for (int j = 0; j < 16; ++j) orow[j] = (float)acc[j];
  }
}

// ---------------- weight transpose + bf16 convert: [E][R][C] -> [E][C][R] ----------------
__global__ __launch_bounds__(256) void cvtT(const float* __restrict__ src, u16* __restrict__ dst,
                                            int R, int C){
  int bx = blockIdx.x;
  int tilesC = C >> 5, tilesR = R >> 5;
  int e = bx / (tilesR*tilesC);
  int rem = bx % (tilesR*tilesC);
  int rt = rem / tilesC, ct = rem % tilesC;
  __shared__ float tile[32][33];
  int t = threadIdx.x;
  int j = t & 31, i0 = t >> 5;
  const float* s = src + (size_t)e*R*C + (size_t)(rt*32)*C + ct*32;
  for (int ii = i0; ii < 32; ii += 8) tile[ii][j] = s[(size_t)ii*C + j];
  __syncthreads();
  u16* d = dst + (size_t)e*R*C + (size_t)(ct*32)*R + rt*32;
  for (int ii = i0; ii < 32; ii += 8) d[(size_t)ii*R + j] = f2bf(tile[j][ii]);
}

// ---------------- layer-2 grouped up-GEMM: bf16 MFMA ----------------
__global__ __launch_bounds__(256) void up_kernel(const u16* __restrict__ hf,
    const u16* __restrict__ w0T, const u16* __restrict__ w1T,
    const int* __restrict__ tok_of, const int* __restrict__ offs, const int* __restrict__ counts,
    u16* __restrict__ hid){
  int bx = blockIdx.x;
  int e  = bx >> 9;
  int mt = (bx >> 3) & 63;
  int nt = bx & 7;
  int base = offs[e], cnt = counts[e];
  int row0 = mt << 7;
  if (row0 >= cnt) return;
  __shared__ __align__(16) u16 Al[2][4096], B0l[2][4096], B1l[2][4096];
  int t = threadIdx.x;
  int rq0 = t >> 2, k8 = t & 3;
  int tok0, tok1;
  { int s0 = base + row0 + rq0;      s0 = s0 < NSLOT_ ? s0 : NSLOT_-1; tok0 = tok_of[s0]; }
  { int s1 = base + row0 + 64 + rq0; s1 = s1 < NSLOT_ ? s1 : NSLOT_-1; tok1 = tok_of[s1]; }
  size_t bcol = (size_t)(e*1024 + nt*128);
  f32x4 acc0[4][4], acc1[4][4];
  #pragma unroll
  for (int i = 0; i < 4; ++i)
    #pragma unroll
    for (int j = 0; j < 4; ++j)
      #pragma unroll
      for (int r = 0; r < 4; ++r){ acc0[i][j][r] = 0.f; acc1[i][j][r] = 0.f; }

#define STAGE_UP(bufi, kc) do{ int kk8 = (kc) + (k8<<3); \
    gl_lds16(hf + ((size_t)tok0<<9) + kk8,        &Al[bufi][t*8]); \
    gl_lds16(hf + ((size_t)tok1<<9) + kk8,        &Al[bufi][2048 + t*8]); \
    gl_lds16(w0T + (bcol + rq0)*512 + kk8,        &B0l[bufi][t*8]); \
    gl_lds16(w0T + (bcol + 64 + rq0)*512 + kk8,   &B0l[bufi][2048 + t*8]); \
    gl_lds16(w1T + (bcol + rq0)*512 + kk8,        &B1l[bufi][t*8]); \
    gl_lds16(w1T + (bcol + 64 + rq0)*512 + kk8,   &B1l[bufi][2048 + t*8]); \
  }while(0)

  int l = t & 63, wid = t >> 6, wm = wid >> 1, wn = wid & 1;
  int lr = l & 15, lk = (l >> 4) << 3;
  STAGE_UP(0, 0);
  for (int ks = 0; ks < 16; ++ks){
    int cur = ks & 1;
    __syncthreads();
    if (ks < 15) STAGE_UP(cur^1, (ks+1)*32);
    bf16x8 av[4], b0[4], b1[4];
    #pragma unroll
    for (int mi = 0; mi < 4; ++mi) av[mi] = *(const bf16x8*)&Al[cur][(wm*64 + mi*16 + lr)*32 + lk];
    #pragma unroll
    for (int ni = 0; ni < 4; ++ni){
      b0[ni] = *(const bf16x8*)&B0l[cur][(wn*64 + ni*16 + lr)*32 + lk];
      b1[ni] = *(const bf16x8*)&B1l[cur][(wn*64 + ni*16 + lr)*32 + lk];
    }
    #pragma unroll
    for (int mi = 0; mi < 4; ++mi)
      #pragma unroll
      for (int ni = 0; ni < 4; ++ni){
        acc0[mi][ni] = __builtin_amdgcn_mfma_f32_16x16x32_bf16(av[mi], b0[ni], acc0[mi][ni], 0, 0, 0);
        acc1[mi][ni] = __builtin_amdgcn_mfma_f32_16x16x32_bf16(av[mi], b1[ni], acc1[mi][ni], 0, 0, 0);
      }
  }
#undef STAGE_UP
  #pragma unroll
  for (int mi = 0; mi < 4; ++mi){
    int rbase = row0 + wm*64 + mi*16 + ((l >> 4) << 2);
    #pragma unroll
    for (int r = 0; r < 4; ++r){
      int rr = rbase + r;
      if (rr < cnt){
        size_t srow = (size_t)(base + rr) << 10;
        int cb = nt*128 + wn*64 + lr;
        #pragma unroll
        for (int ni = 0; ni < 4; ++ni){
          float u0 = acc0[mi][ni][r];
          float u1 = acc1[mi][ni][r];
          u0 = u0 > 0.f ? u0 : 0.f;
          hid[srow + cb + ni*16] = f2bf(u0*u1);
        }
      }
    }
  }
}

// ---------------- layer-2 grouped down-GEMM: bf16 MFMA ----------------
__global__ __launch_bounds__(256) void down_kernel(const u16* __restrict__ hid,
    const u16* __restrict__ woT, const int* __restrict__ offs, const int* __restrict__ counts,
    float* __restrict__ eo){
  int bx = blockIdx.x;
  int e  = bx >> 8;
  int mt = (bx >> 2) & 63;
  int nt = bx & 3;
  int base = offs[e], cnt = counts[e];
  int row0 = mt << 7;
  if (row0 >= cnt) return;
  __shared__ __align__(16) u16 Al[2][4096], Bl[2][4096];
  int t = threadIdx.x;
  int rq = t >> 2, k8 = t & 3;
  int r0 = base + row0 + rq;      r0 = r0 < NSLOT_ ? r0 : NSLOT_-1;
  int r1 = base + row0 + 64 + rq; r1 = r1 < NSLOT_ ? r1 : NSLOT_-1;
  size_t bcol = (size_t)(e*512 + nt*128);
  f32x4 acc[4][4];
  #pragma unroll
  for (int i = 0; i < 4; ++i)
    #pragma unroll
    for (int j = 0; j < 4; ++j)
      #pragma unroll
      for (int r = 0; r < 4; ++r) acc[i][j][r] = 0.f;

#define STAGE_DN(bufi, kc) do{ int kk8 = (kc) + (k8<<3); \
    gl_lds16(hid + ((size_t)r0<<10) + kk8,         &Al[bufi][t*8]); \
    gl_lds16(hid + ((size_t)r1<<10) + kk8,         &Al[bufi][2048 + t*8]); \
    gl_lds16(woT + (bcol + rq)*1024 + kk8,         &Bl[bufi][t*8]); \
    gl_lds16(woT + (bcol + 64 + rq)*1024 + kk8,    &Bl[bufi][2048 + t*8]); \
  }while(0)

  int l = t & 63, wid = t >> 6, wm = wid >> 1, wn = wid & 1;
  int lr = l & 15, lk = (l >> 4) << 3;
  STAGE_DN(0, 0);
  for (int ks = 0; ks < 32; ++ks){
    int cur = ks & 1;
    __syncthreads();
    if (ks < 31) STAGE_DN(cur^1, (ks+1)*32);
    bf16x8 av[4], bv[4];
    #pragma unroll
    for (int mi = 0; mi < 4; ++mi) av[mi] = *(const bf16x8*)&Al[cur][(wm*64 + mi*16 + lr)*32 + lk];
    #pragma unroll
    for (int ni = 0; ni < 4; ++ni) bv[ni] = *(const bf16x8*)&Bl[cur][(wn*64 + ni*16 + lr)*32 + lk];
    #pragma unroll
    for (int mi = 0; mi < 4; ++mi)
      #pragma unroll
      for (int ni = 0; ni < 4; ++ni)
        acc[mi][ni] = __builtin_amdgcn_mfma_f32_16x16x32_bf16(av[mi], bv[ni], acc[mi][ni], 0, 0, 0);
  }
#undef STAGE_DN
  #pragma unroll
  for (int mi = 0; mi < 4; ++mi){
    int rbase = row0 + wm*64 + mi*16 + ((l >> 4) << 2);
    #pragma unroll
    for (int r = 0; r < 4; ++r){
      int rr = rbase + r;
      if (rr < cnt){
        size_t srow = (size_t)(base + rr) << 9;
        int cb = nt*128 + wn*64 + lr;
        #pragma unroll
        for (int ni = 0; ni < 4; ++ni)
          eo[srow + cb + ni*16] = acc[mi][ni][r];
      }
    }
  }
}

// ---------------- gather + residual ----------------
__global__ __launch_bounds__(128) void gather_kernel(const float* __restrict__ xin,
    const float* __restrict__ eo, const int* __restrict__ slot_of, const float* __restrict__ wv,
    float* __restrict__ out){
  int n = blockIdx.x, t = threadIdx.x;
  int s0 = slot_of[2*n], s1 = slot_of[2*n+1];
  double w0 = wv[2*n], w1 = wv[2*n+1];
  float4 xi = *(const float4*)&xin[((size_t)n << 9) + t*4];
  float4 e0 = *(const float4*)&eo[((size_t)s0 << 9) + t*4];
  float4 e1 = *(const float4*)&eo[((size_t)s1 << 9) + t*4];
  float4 o;
  o.x = (float)((double)xi.x + w0*(double)e0.x + w1*(double)e1.x);
  o.y = (float)((double)xi.y + w0*(double)e0.y + w1*(double)e1.y);
  o.z = (float)((double)xi.z + w0*(double)e0.z + w1*(double)e1.z);
  o.w = (float)((double)xi.w + w0*(double)e0.w + w1*(double)e1.w);
  *(float4*)&out[((size_t)n << 9) + t*4] = o;
}

extern "C" void kernel_launch(void* const* d_in, const int* in_sizes, int n_in,
                              void* d_out, int out_size, void* d_ws, size_t ws_size,
                              hipStream_t stream) {
  (void)in_sizes; (void)n_in; (void)out_size; (void)ws_size;
  const float* x0   = (const float*)d_in[0];
  const int*   sid  = (const int*)  d_in[1];
  const float* ln_g = (const float*)d_in[2];
  const float* ln_b = (const float*)d_in[3];
  const float* semb = (const float*)d_in[4];
  const float* h1w  = (const float*)d_in[5];
  const float* h1b  = (const float*)d_in[6];
  const float* h2w  = (const float*)d_in[7];
  const float* h2b  = (const float*)d_in[8];
  const float* s1w  = (const float*)d_in[9];
  const float* s1b  = (const float*)d_in[10];
  const float* s2w  = (const float*)d_in[11];
  const float* s2b  = (const float*)d_in[12];
  const float* g1w  = (const float*)d_in[13];
  const float* g1b  = (const float*)d_in[14];
  const float* g2w  = (const float*)d_in[15];
  const float* g2b  = (const float*)d_in[16];
  const float* wi0  = (const float*)d_in[17];
  const float* wi1  = (const float*)d_in[18];
  const float* wo   = (const float*)d_in[19];

  char* W = (char*)d_ws;
  double* h64    = (double*)(W + 0);                    // 33,554,432
  float*  hf32   = (float*) (W + 33554432ULL);          // 16,777,216
  u16*    hfb    = (u16*)   (W + 50331648ULL);          //  8,388,608
  float*  hid32  = (float*) (W + 58720256ULL);          // 67,108,864 (layer1)
  u16*    hidb   = (u16*)   (W + 58720256ULL);          // overlay (layer2)
  float*  eo32   = (float*) (W + 125829120ULL);         // 33,554,432
  u16*    wi0T   = (u16*)   (W + 159383552ULL);
  u16*    wi1T   = (u16*)   (W + 167772160ULL);
  u16*    woT    = (u16*)   (W + 176160768ULL);
  double* cs     = (double*)(W + 184549376ULL);
  double* cq     = (double*)(W + 184582144ULL);
  double* a64    = (double*)(W + 184614912ULL);
  double* c64    = (double*)(W + 184647680ULL);
  int*    idxa   = (int*)   (W + 184680448ULL);
  float*  warr   = (float*) (W + 184745984ULL);
  int*    tok_of = (int*)   (W + 184811520ULL);
  int*    slot_of= (int*)   (W + 184877056ULL);
  int*    counts = (int*)   (W + 184942592ULL);
  int*    cur    = counts + 8;
  int*    offs   = counts + 16;

  cvtT<<<4096, 256, 0, stream>>>(wi0, wi0T, 512, 1024);
  cvtT<<<4096, 256, 0, stream>>>(wi1, wi1T, 512, 1024);
  cvtT<<<4096, 256, 0, stream>>>(wo,  woT,  1024, 512);

  for (int l = 0; l < 2; ++l){
    const float* xin = l ? (const float*)d_out : x0;
    ln_kernel<<<8192, 256, 0, stream>>>(xin, ln_g + l*512, ln_b + l*512, h64);
    colstats<<<64, 256, 0, stream>>>(h64, cs, cq);
    subj_kernel<<<1, 256, 0, stream>>>(sid, semb, h1w, h1b, h2w, h2b, s1w, s1b, s2w, s2b,
                                       cs, cq, a64, c64, l);
    hfcast<<<2048, 256, 0, stream>>>(h64, a64, c64, hf32, hfb);
    zero_counts<<<1, 64, 0, stream>>>(counts);
    gate_kernel<<<256, 256, 0, stream>>>(h64, a64, c64, g1w, g1b, g2w, g2b, idxa, warr, counts);
    offsets_kernel<<<1, 1, 0, stream>>>(counts, offs, cur);
    scatter_kernel<<<32, 256, 0, stream>>>(idxa, offs, cur, tok_of, slot_of);
    if (l == 0){
      up1_kernel<<<32768, 256, 0, stream>>>(hf32, wi0, wi1, tok_of, offs, counts, hid32);
      down1_kernel<<<8192, 256, 0, stream>>>(hid32, wo, offs, counts, eo32);
    } else {
      up_kernel<<<4096, 256, 0, stream>>>(hfb, wi0T, wi1T, tok_of, offs, counts, hidb);
      down_kernel<<<2048, 256, 0, stream>>>(hidb, woT, offs, counts, eo32);
    }
    gather_kernel<<<8192, 128, 0, stream>>>(xin, eo32, slot_of, warr, (float*)d_out);
  }
}

// Round 3
// 1265.218 us; speedup vs baseline: 2.4409x; 2.4409x over previous
//
#include <hip/hip_runtime.h>

typedef unsigned short u16;
typedef unsigned int   u32;
typedef _Float16       f16;
typedef __attribute__((ext_vector_type(8))) __bf16   bf16x8;
typedef __attribute__((ext_vector_type(8))) _Float16 f16x8;
typedef __attribute__((ext_vector_type(4))) float    f32x4;
typedef __attribute__((ext_vector_type(8))) short    short8;
typedef __attribute__((ext_vector_type(4))) double   dbl4;

#define NSLOT_ 16384   // N * K = 8192 * 2

__device__ __forceinline__ u16 f2bf(float f){
  u32 u = __float_as_uint(f);
  u32 lsb = (u >> 16) & 1u;
  u += 0x7fffu + lsb;
  return (u16)(u >> 16);
}
__device__ __forceinline__ u16 f16bits(f16 h){ union{f16 f; u16 u;} x; x.f = h; return x.u; }

__device__ __forceinline__ void gl_lds16(const void* gptr, void* lptr){
  __builtin_amdgcn_global_load_lds((const __attribute__((address_space(1))) u32*)gptr,
                                   (__attribute__((address_space(3))) u32*)lptr, 16, 0, 0);
}

// ---------------- per-token LayerNorm over D=512 (f64 math, f32 out) ----------------
__global__ __launch_bounds__(256) void ln_kernel(const float* __restrict__ x,
    const float* __restrict__ g, const float* __restrict__ bb, float* __restrict__ h){
  int n = blockIdx.x, t = threadIdx.x;
  const float* xr = x + ((size_t)n << 9);
  float2 v = *(const float2*)&xr[t*2];
  double vx = v.x, vy = v.y;
  double s = vx + vy;
  double q = vx*vx + vy*vy;
  #pragma unroll
  for (int o = 32; o > 0; o >>= 1){ s += __shfl_down(s, o, 64); q += __shfl_down(q, o, 64); }
  __shared__ double ls[4], lq_[4];
  __shared__ double sm, sv;
  int wid = t >> 6, lane = t & 63;
  if (lane == 0){ ls[wid] = s; lq_[wid] = q; }
  __syncthreads();
  if (t == 0){
    double S = ls[0]+ls[1]+ls[2]+ls[3], Q = lq_[0]+lq_[1]+lq_[2]+lq_[3];
    double mean = S * (1.0/512.0);
    double var  = Q * (1.0/512.0) - mean*mean;
    sm = mean; sv = 1.0/sqrt(var + 1e-5);
  }
  __syncthreads();
  double mean = sm, inv = sv;
  int d = t*2;
  float2 o;
  o.x = (float)((vx - mean)*inv*(double)g[d]   + (double)bb[d]);
  o.y = (float)((vy - mean)*inv*(double)g[d+1] + (double)bb[d+1]);
  *(float2*)&h[((size_t)n<<9) + d] = o;
}

// ---------------- column stats over T per (b,d), f64 accum from f32 h ----------------
__global__ __launch_bounds__(256) void colstats(const float* __restrict__ h,
    double* __restrict__ cs, double* __restrict__ cq){
  int bid = blockIdx.x;
  int b = bid >> 3, ch = bid & 7;
  int t = threadIdx.x;
  int col = ch*64 + (t & 63);
  int tp = t >> 6;
  const float* base = h + ((size_t)b << 19);
  double s = 0.0, q = 0.0;
  for (int tt = tp; tt < 1024; tt += 4){
    double v = (double)base[((size_t)tt << 9) + col];
    s += v; q += v*v;
  }
  __shared__ double ls[4][64], lq[4][64];
  ls[tp][t & 63] = s; lq[tp][t & 63] = q;
  __syncthreads();
  if (tp == 0){
    double S = ls[0][t]+ls[1][t]+ls[2][t]+ls[3][t];
    double Q = lq[0][t]+lq[1][t]+lq[2][t]+lq[3][t];
    cs[(b<<9)+col] = S; cq[(b<<9)+col] = Q;
  }
}

// ---------------- subject MLP -> per-(b,d) affine a,c (f64) ----------------
__global__ __launch_bounds__(256) void subj_kernel(const int* __restrict__ sid,
    const float* __restrict__ semb,
    const float* __restrict__ h1w, const float* __restrict__ h1b,
    const float* __restrict__ h2w, const float* __restrict__ h2b,
    const float* __restrict__ s1w, const float* __restrict__ s1b,
    const float* __restrict__ s2w, const float* __restrict__ s2b,
    const double* __restrict__ cs, const double* __restrict__ cq,
    double* __restrict__ a64, double* __restrict__ c64, int l){
  __shared__ double ev[64], hid1[128], hh[128], sh[64], sp[1024];
  int t = threadIdx.x;
  for (int b = 0; b < 8; ++b){
    int s = sid[b];
    if (t < 64) ev[t] = (double)semb[l*4096 + s*64 + t];
    __syncthreads();
    if (t < 128){
      double acc = (double)h1b[l*128 + t];
      for (int i = 0; i < 64; ++i) acc += ev[i]*(double)h1w[l*8192 + i*128 + t];
      hid1[t] = acc > 0.0 ? acc : 0.0;
    }
    __syncthreads();
    if (t < 128){
      double acc = (double)h2b[l*128 + t];
      for (int i = 0; i < 128; ++i) acc += hid1[i]*(double)h2w[l*16384 + i*128 + t];
      hh[t] = acc;
    }
    __syncthreads();
    if (t < 64){
      double acc = (double)s1b[l*64 + t];
      for (int i = 0; i < 128; ++i) acc += hh[i]*(double)s1w[l*8192 + i*64 + t];
      sh[t] = acc > 0.0 ? acc : 0.0;
    }
    __syncthreads();
    for (int m = t; m < 1024; m += 256){
      double acc = (double)s2b[l*1024 + m];
      for (int j = 0; j < 64; ++j) acc += sh[j]*(double)s2w[l*65536 + j*1024 + m];
      sp[m] = acc;
    }
    __syncthreads();
    for (int d = t; d < 512; d += 256){
      double mu  = cs[(b<<9)+d] * (1.0/1024.0);
      double var = cq[(b<<9)+d] * (1.0/1024.0) - mu*mu;
      double inv = 1.0/sqrt(var + 1e-8);
      double spv = sp[d];
      double gamma = (spv > 30.0 ? spv : log1p(exp(spv))) + 1e-8;
      double beta  = sp[512 + d];
      double A = gamma * inv;
      a64[(b<<9)+d] = A;
      c64[(b<<9)+d] = beta - mu*A;
    }
    __syncthreads();
  }
}

// ---------------- hf = h*a + c -> fp16 hi/lo' (lo scaled 2^11) + bf16 ----------------
__global__ __launch_bounds__(256) void hfcast(const float* __restrict__ h,
    const double* __restrict__ a64, const double* __restrict__ c64,
    u16* __restrict__ hfh, u16* __restrict__ hfl, u16* __restrict__ hfb){
  size_t i0 = ((size_t)blockIdx.x*256 + threadIdx.x) * 8;
  int n = (int)(i0 >> 9);
  int d0 = (int)(i0 & 511);
  int b = n >> 10;
  float4 x0 = *(const float4*)&h[i0];
  float4 x1 = *(const float4*)&h[i0 + 4];
  dbl4 a0 = *(const dbl4*)&a64[(b<<9) + d0];
  dbl4 a1 = *(const dbl4*)&a64[(b<<9) + d0 + 4];
  dbl4 c0 = *(const dbl4*)&c64[(b<<9) + d0];
  dbl4 c1 = *(const dbl4*)&c64[(b<<9) + d0 + 4];
  float f[8];
  f[0] = (float)((double)x0.x*a0[0] + c0[0]);
  f[1] = (float)((double)x0.y*a0[1] + c0[1]);
  f[2] = (float)((double)x0.z*a0[2] + c0[2]);
  f[3] = (float)((double)x0.w*a0[3] + c0[3]);
  f[4] = (float)((double)x1.x*a1[0] + c1[0]);
  f[5] = (float)((double)x1.y*a1[1] + c1[1]);
  f[6] = (float)((double)x1.z*a1[2] + c1[2]);
  f[7] = (float)((double)x1.w*a1[3] + c1[3]);
  short8 oh, ol, ob;
  #pragma unroll
  for (int j = 0; j < 8; ++j){
    f16 hi = (f16)f[j];
    float rem = (f[j] - (float)hi) * 2048.f;
    f16 lo = (f16)rem;
    oh[j] = (short)f16bits(hi);
    ol[j] = (short)f16bits(lo);
    ob[j] = (short)f2bf(f[j]);
  }
  *(short8*)&hfh[i0] = oh;
  *(short8*)&hfl[i0] = ol;
  *(short8*)&hfb[i0] = ob;
}

__global__ void zero_counts(int* __restrict__ counts){
  if (threadIdx.x < 8) counts[threadIdx.x] = 0;
}

// ---------------- gating: f64 math from f32 h, top-2 ----------------
__global__ __launch_bounds__(256) void gate_kernel(const float* __restrict__ h,
    const double* __restrict__ a64, const double* __restrict__ c64,
    const float* __restrict__ g1w, const float* __restrict__ g1b,
    const float* __restrict__ g2w, const float* __restrict__ g2b,
    int* __restrict__ idxo, float* __restrict__ wo_, int* __restrict__ counts){
  __shared__ double hfT[64*32];
  __shared__ __align__(16) double ovl[8192];
  __shared__ double lg[32*8];
  __shared__ int lcnt[8];
  float*  g1s   = (float*)ovl;
  double* hid_s = ovl;
  int t = threadIdx.x;
  int tok0 = blockIdx.x << 5;
  int b = tok0 >> 10;
  if (t < 8) lcnt[t] = 0;
  double acc[32];
  #pragma unroll
  for (int i = 0; i < 32; ++i) acc[i] = 0.0;
  int r_st = t & 31, kp_st = t >> 5;
  int tokr = (t >> 6) << 3, col0 = (t & 63) << 2;
  for (int kc = 0; kc < 512; kc += 64){
    {
      int dbase = kc + (kp_st << 3);
      const float* hrow = h + (((size_t)(tok0 + r_st)) << 9) + dbase;
      float4 x0 = *(const float4*)hrow;
      float4 x1 = *(const float4*)(hrow + 4);
      dbl4 a0 = *(const dbl4*)&a64[(b<<9) + dbase];
      dbl4 a1 = *(const dbl4*)&a64[(b<<9) + dbase + 4];
      dbl4 c0 = *(const dbl4*)&c64[(b<<9) + dbase];
      dbl4 c1 = *(const dbl4*)&c64[(b<<9) + dbase + 4];
      hfT[((kp_st<<3)+0)*32 + r_st] = (double)x0.x*a0[0] + c0[0];
      hfT[((kp_st<<3)+1)*32 + r_st] = (double)x0.y*a0[1] + c0[1];
      hfT[((kp_st<<3)+2)*32 + r_st] = (double)x0.z*a0[2] + c0[2];
      hfT[((kp_st<<3)+3)*32 + r_st] = (double)x0.w*a0[3] + c0[3];
      hfT[((kp_st<<3)+4)*32 + r_st] = (double)x1.x*a1[0] + c1[0];
      hfT[((kp_st<<3)+5)*32 + r_st] = (double)x1.y*a1[1] + c1[1];
      hfT[((kp_st<<3)+6)*32 + r_st] = (double)x1.z*a1[2] + c1[2];
      hfT[((kp_st<<3)+7)*32 + r_st] = (double)x1.w*a1[3] + c1[3];
    }
    #pragma unroll
    for (int i = 0; i < 16; ++i){
      int f4 = (i << 8) + t;
      int row = f4 >> 6, c4 = (f4 & 63) << 2;
      *(float4*)&g1s[(row << 8) + c4] = *(const float4*)&g1w[((size_t)(kc+row) << 8) + c4];
    }
    __syncthreads();
    for (int kk = 0; kk < 64; ++kk){
      float4 gv = *(const float4*)&g1s[(kk << 8) + col0];
      double g0 = gv.x, g1 = gv.y, g2 = gv.z, g3 = gv.w;
      const double* hp = &hfT[(kk << 5) + tokr];
      #pragma unroll
      for (int tr = 0; tr < 8; ++tr){
        double hv = hp[tr];
        acc[tr*4+0] = fma(hv, g0, acc[tr*4+0]);
        acc[tr*4+1] = fma(hv, g1, acc[tr*4+1]);
        acc[tr*4+2] = fma(hv, g2, acc[tr*4+2]);
        acc[tr*4+3] = fma(hv, g3, acc[tr*4+3]);
      }
    }
    __syncthreads();
  }
  #pragma unroll
  for (int tr = 0; tr < 8; ++tr){
    #pragma unroll
    for (int cc = 0; cc < 4; ++cc){
      double v = acc[tr*4+cc] + (double)g1b[col0+cc];
      hid_s[(tokr+tr)*256 + col0 + cc] = v > 0.0 ? v : 0.0;
    }
  }
  __syncthreads();
  {
    int tok = t >> 3, e = t & 7;
    double la = (double)g2b[e];
    for (int k = 0; k < 256; ++k) la += hid_s[(tok<<8)+k]*(double)g2w[(k<<3)+e];
    lg[(tok<<3)+e] = la;
  }
  __syncthreads();
  if (t < 32){
    double l0[8];
    #pragma unroll
    for (int e = 0; e < 8; ++e) l0[e] = lg[(t<<3)+e];
    double m = l0[0];
    #pragma unroll
    for (int e = 1; e < 8; ++e) m = fmax(m, l0[e]);
    double p[8]; double s = 0.0;
    #pragma unroll
    for (int e = 0; e < 8; ++e){ p[e] = exp(l0[e]-m); s += p[e]; }
    double b1 = -1e300, b2 = -1e300; int i1 = 0, i2 = 1;
    #pragma unroll
    for (int e = 0; e < 8; ++e){
      double v = l0[e];
      if (v > b1){ b2 = b1; i2 = i1; b1 = v; i1 = e; }
      else if (v > b2){ b2 = v; i2 = e; }
    }
    double pr1 = p[i1]/s, pr2 = p[i2]/s;
    double den = pr1 + pr2 + 1e-8;
    int n = tok0 + t;
    idxo[2*n] = i1; idxo[2*n+1] = i2;
    wo_[2*n] = (float)(pr1/den); wo_[2*n+1] = (float)(pr2/den);
    atomicAdd(&lcnt[i1], 1); atomicAdd(&lcnt[i2], 1);
  }
  __syncthreads();
  if (t < 8) atomicAdd(&counts[t], lcnt[t]);
}

__global__ void offsets_kernel(const int* __restrict__ counts, int* __restrict__ offs,
                               int* __restrict__ cur){
  if (threadIdx.x == 0 && blockIdx.x == 0){
    int run = 0;
    for (int e = 0; e < 8; ++e){ offs[e] = run; run += counts[e]; cur[e] = 0; }
  }
}

__global__ __launch_bounds__(256) void scatter_kernel(const int* __restrict__ idx,
    const int* __restrict__ offs, int* __restrict__ cur,
    int* __restrict__ tok_of, int* __restrict__ slot_of){
  __shared__ int lcnt[8], lbase[8];
  int t = threadIdx.x;
  int n = blockIdx.x*256 + t;
  if (t < 8) lcnt[t] = 0;
  __syncthreads();
  int e0 = idx[2*n], e1 = idx[2*n+1];
  int p0 = atomicAdd(&lcnt[e0], 1);
  int p1 = atomicAdd(&lcnt[e1], 1);
  __syncthreads();
  if (t < 8) lbase[t] = atomicAdd(&cur[t], lcnt[t]);
  __syncthreads();
  int s0 = offs[e0] + lbase[e0] + p0;
  int s1 = offs[e1] + lbase[e1] + p1;
  tok_of[s0] = n; tok_of[s1] = n;
  slot_of[2*n] = s0; slot_of[2*n+1] = s1;
}

// ---------------- weight transpose: [E][R][C] f32 -> [E][C][R] bf16 ----------------
__global__ __launch_bounds__(256) void cvtT(const float* __restrict__ src, u16* __restrict__ dst,
                                            int R, int C){
  int bx = blockIdx.x;
  int tilesC = C >> 5, tilesR = R >> 5;
  int e = bx / (tilesR*tilesC);
  int rem = bx % (tilesR*tilesC);
  int rt = rem / tilesC, ct = rem % tilesC;
  __shared__ float tile[32][33];
  int t = threadIdx.x;
  int j = t & 31, i0 = t >> 5;
  const float* s = src + (size_t)e*R*C + (size_t)(rt*32)*C + ct*32;
  for (int ii = i0; ii < 32; ii += 8) tile[ii][j] = s[(size_t)ii*C + j];
  __syncthreads();
  u16* d = dst + (size_t)e*R*C + (size_t)(ct*32)*R + rt*32;
  for (int ii = i0; ii < 32; ii += 8) d[(size_t)ii*R + j] = f2bf(tile[j][ii]);
}

// ---------------- weight transpose + fp16 hi/lo' split ----------------
__global__ __launch_bounds__(256) void cvtT16(const float* __restrict__ src,
    u16* __restrict__ dh, u16* __restrict__ dl, int R, int C){
  int bx = blockIdx.x;
  int tilesC = C >> 5, tilesR = R >> 5;
  int e = bx / (tilesR*tilesC);
  int rem = bx % (tilesR*tilesC);
  int rt = rem / tilesC, ct = rem % tilesC;
  __shared__ float tile[32][33];
  int t = threadIdx.x;
  int j = t & 31, i0 = t >> 5;
  const float* s = src + (size_t)e*R*C + (size_t)(rt*32)*C + ct*32;
  for (int ii = i0; ii < 32; ii += 8) tile[ii][j] = s[(size_t)ii*C + j];
  __syncthreads();
  size_t ob = (size_t)e*R*C + (size_t)(ct*32)*R + rt*32;
  for (int ii = i0; ii < 32; ii += 8){
    float v = tile[j][ii];
    f16 hi = (f16)v;
    float rem2 = (v - (float)hi) * 2048.f;
    f16 lo = (f16)rem2;
    dh[ob + (size_t)ii*R + j] = f16bits(hi);
    dl[ob + (size_t)ii*R + j] = f16bits(lo);
  }
}

// ---------------- layer-1 up-GEMM: fp16-split MFMA, dual output ----------------
// grid: e(8) x mt(64, 128 rows) x nt(16, 64 cols)
__global__ __launch_bounds__(256) void up1_kernel(const u16* __restrict__ hfh,
    const u16* __restrict__ hfl,
    const u16* __restrict__ w0h, const u16* __restrict__ w0l,
    const u16* __restrict__ w1h, const u16* __restrict__ w1l,
    const int* __restrict__ tok_of, const int* __restrict__ offs, const int* __restrict__ counts,
    u16* __restrict__ hidh, u16* __restrict__ hidl){
  int bx = blockIdx.x;
  int e  = bx >> 10;
  int mt = (bx >> 4) & 63;
  int nt = bx & 15;
  int base = offs[e], cnt = counts[e];
  int row0 = mt << 7;
  if (row0 >= cnt) return;
  __shared__ __align__(16) u16 Ah[2][4096], Alo[2][4096],
                               B0h[2][2048], B0l[2][2048], B1h[2][2048], B1l[2][2048];
  int t = threadIdx.x;
  int rq0 = t >> 2, k8 = (t & 3) << 3;
  int tok0, tok1;
  { int s0 = base + row0 + rq0;      s0 = s0 < NSLOT_ ? s0 : NSLOT_-1; tok0 = tok_of[s0]; }
  { int s1 = base + row0 + 64 + rq0; s1 = s1 < NSLOT_ ? s1 : NSLOT_-1; tok1 = tok_of[s1]; }
  size_t bw = (size_t)e*524288 + (size_t)(nt*64 + rq0)*512;
  f32x4 hh0[4][2], cr0[4][2], hh1[4][2], cr1[4][2];
  #pragma unroll
  for (int i = 0; i < 4; ++i)
    #pragma unroll
    for (int j = 0; j < 2; ++j)
      #pragma unroll
      for (int r = 0; r < 4; ++r){ hh0[i][j][r]=0.f; cr0[i][j][r]=0.f; hh1[i][j][r]=0.f; cr1[i][j][r]=0.f; }

#define STG_UP(bufi, kc) do{ int kk = (kc) + k8; \
    gl_lds16(hfh + ((size_t)tok0<<9) + kk, &Ah[bufi][rq0*32 + k8]); \
    gl_lds16(hfh + ((size_t)tok1<<9) + kk, &Ah[bufi][2048 + rq0*32 + k8]); \
    gl_lds16(hfl + ((size_t)tok0<<9) + kk, &Alo[bufi][rq0*32 + k8]); \
    gl_lds16(hfl + ((size_t)tok1<<9) + kk, &Alo[bufi][2048 + rq0*32 + k8]); \
    gl_lds16(w0h + bw + kk, &B0h[bufi][rq0*32 + k8]); \
    gl_lds16(w0l + bw + kk, &B0l[bufi][rq0*32 + k8]); \
    gl_lds16(w1h + bw + kk, &B1h[bufi][rq0*32 + k8]); \
    gl_lds16(w1l + bw + kk, &B1l[bufi][rq0*32 + k8]); \
  }while(0)

  int l = t & 63, wid = t >> 6, wm = wid >> 1, wn = wid & 1;
  int lr = l & 15, lk = (l >> 4) << 3;
  STG_UP(0, 0);
  for (int ks = 0; ks < 16; ++ks){
    int cur = ks & 1;
    __syncthreads();
    if (ks < 15) STG_UP(cur^1, (ks+1)*32);
    f16x8 ah[4], al[4];
    #pragma unroll
    for (int mi = 0; mi < 4; ++mi){
      int o = (wm*64 + mi*16 + lr)*32 + lk;
      ah[mi] = *(const f16x8*)&Ah[cur][o];
      al[mi] = *(const f16x8*)&Alo[cur][o];
    }
    f16x8 b0hv[2], b0lv[2], b1hv[2], b1lv[2];
    #pragma unroll
    for (int ni = 0; ni < 2; ++ni){
      int o = (wn*32 + ni*16 + lr)*32 + lk;
      b0hv[ni] = *(const f16x8*)&B0h[cur][o];
      b0lv[ni] = *(const f16x8*)&B0l[cur][o];
      b1hv[ni] = *(const f16x8*)&B1h[cur][o];
      b1lv[ni] = *(const f16x8*)&B1l[cur][o];
    }
    #pragma unroll
    for (int mi = 0; mi < 4; ++mi)
      #pragma unroll
      for (int ni = 0; ni < 2; ++ni){
        hh0[mi][ni] = __builtin_amdgcn_mfma_f32_16x16x32_f16(ah[mi], b0hv[ni], hh0[mi][ni], 0, 0, 0);
        cr0[mi][ni] = __builtin_amdgcn_mfma_f32_16x16x32_f16(ah[mi], b0lv[ni], cr0[mi][ni], 0, 0, 0);
        cr0[mi][ni] = __builtin_amdgcn_mfma_f32_16x16x32_f16(al[mi], b0hv[ni], cr0[mi][ni], 0, 0, 0);
        hh1[mi][ni] = __builtin_amdgcn_mfma_f32_16x16x32_f16(ah[mi], b1hv[ni], hh1[mi][ni], 0, 0, 0);
        cr1[mi][ni] = __builtin_amdgcn_mfma_f32_16x16x32_f16(ah[mi], b1lv[ni], cr1[mi][ni], 0, 0, 0);
        cr1[mi][ni] = __builtin_amdgcn_mfma_f32_16x16x32_f16(al[mi], b1hv[ni], cr1[mi][ni], 0, 0, 0);
      }
  }
#undef STG_UP
  #pragma unroll
  for (int mi = 0; mi < 4; ++mi){
    int rbase = row0 + wm*64 + mi*16 + ((l >> 4) << 2);
    #pragma unroll
    for (int r = 0; r < 4; ++r){
      int rr = rbase + r;
      if (rr < cnt){
        size_t orow = ((size_t)(base + rr) << 10) + nt*64 + wn*32 + lr;
        #pragma unroll
        for (int ni = 0; ni < 2; ++ni){
          float u0 = hh0[mi][ni][r] + cr0[mi][ni][r]*(1.f/2048.f);
          float u1 = hh1[mi][ni][r] + cr1[mi][ni][r]*(1.f/2048.f);
          u0 = u0 > 0.f ? u0 : 0.f;
          float v = u0*u1;
          f16 vh = (f16)v;
          float rem2 = (v - (float)vh)*2048.f;
          f16 vl = (f16)rem2;
          hidh[orow + ni*16] = f16bits(vh);
          hidl[orow + ni*16] = f16bits(vl);
        }
      }
    }
  }
}

// ---------------- layer-1 down-GEMM: fp16-split MFMA ----------------
// grid: e(8) x mt(64, 128 rows) x nt(8, 64 cols)
__global__ __launch_bounds__(256) void down1_kernel(const u16* __restrict__ hidh,
    const u16* __restrict__ hidl,
    const u16* __restrict__ wdh, const u16* __restrict__ wdl,
    const int* __restrict__ offs, const int* __restrict__ counts,
    float* __restrict__ eo){
  int bx = blockIdx.x;
  int e  = bx >> 9;
  int mt = (bx >> 3) & 63;
  int nt = bx & 7;
  int base = offs[e], cnt = counts[e];
  int row0 = mt << 7;
  if (row0 >= cnt) return;
  __shared__ __align__(16) u16 Ah[2][4096], Alo[2][4096], Bh[2][2048], Bl[2][2048];
  int t = threadIdx.x;
  int rq0 = t >> 2, k8 = (t & 3) << 3;
  int r0 = base + row0 + rq0;      r0 = r0 < NSLOT_ ? r0 : NSLOT_-1;
  int r1 = base + row0 + 64 + rq0; r1 = r1 < NSLOT_ ? r1 : NSLOT_-1;
  size_t bw = (size_t)e*524288 + (size_t)(nt*64 + rq0)*1024;
  f32x4 hh[4][2], cr[4][2];
  #pragma unroll
  for (int i = 0; i < 4; ++i)
    #pragma unroll
    for (int j = 0; j < 2; ++j)
      #pragma unroll
      for (int r = 0; r < 4; ++r){ hh[i][j][r]=0.f; cr[i][j][r]=0.f; }

#define STG_DN(bufi, kc) do{ int kk = (kc) + k8; \
    gl_lds16(hidh + ((size_t)r0<<10) + kk, &Ah[bufi][rq0*32 + k8]); \
    gl_lds16(hidh + ((size_t)r1<<10) + kk, &Ah[bufi][2048 + rq0*32 + k8]); \
    gl_lds16(hidl + ((size_t)r0<<10) + kk, &Alo[bufi][rq0*32 + k8]); \
    gl_lds16(hidl + ((size_t)r1<<10) + kk, &Alo[bufi][2048 + rq0*32 + k8]); \
    gl_lds16(wdh + bw + kk, &Bh[bufi][rq0*32 + k8]); \
    gl_lds16(wdl + bw + kk, &Bl[bufi][rq0*32 + k8]); \
  }while(0)

  int l = t & 63, wid = t >> 6, wm = wid >> 1, wn = wid & 1;
  int lr = l & 15, lk = (l >> 4) << 3;
  STG_DN(0, 0);
  for (int ks = 0; ks < 32; ++ks){
    int cur = ks & 1;
    __syncthreads();
    if (ks < 31) STG_DN(cur^1, (ks+1)*32);
    f16x8 ah[4], al[4];
    #pragma unroll
    for (int mi = 0; mi < 4; ++mi){
      int o = (wm*64 + mi*16 + lr)*32 + lk;
      ah[mi] = *(const f16x8*)&Ah[cur][o];
      al[mi] = *(const f16x8*)&Alo[cur][o];
    }
    f16x8 bh[2], bl[2];
    #pragma unroll
    for (int ni = 0; ni < 2; ++ni){
      int o = (wn*32 + ni*16 + lr)*32 + lk;
      bh[ni] = *(const f16x8*)&Bh[cur][o];
      bl[ni] = *(const f16x8*)&Bl[cur][o];
    }
    #pragma unroll
    for (int mi = 0; mi < 4; ++mi)
      #pragma unroll
      for (int ni = 0; ni < 2; ++ni){
        hh[mi][ni] = __builtin_amdgcn_mfma_f32_16x16x32_f16(ah[mi], bh[ni], hh[mi][ni], 0, 0, 0);
        cr[mi][ni] = __builtin_amdgcn_mfma_f32_16x16x32_f16(ah[mi], bl[ni], cr[mi][ni], 0, 0, 0);
        cr[mi][ni] = __builtin_amdgcn_mfma_f32_16x16x32_f16(al[mi], bh[ni], cr[mi][ni], 0, 0, 0);
      }
  }
#undef STG_DN
  #pragma unroll
  for (int mi = 0; mi < 4; ++mi){
    int rbase = row0 + wm*64 + mi*16 + ((l >> 4) << 2);
    #pragma unroll
    for (int r = 0; r < 4; ++r){
      int rr = rbase + r;
      if (rr < cnt){
        size_t orow = ((size_t)(base + rr) << 9) + nt*64 + wn*32 + lr;
        #pragma unroll
        for (int ni = 0; ni < 2; ++ni)
          eo[orow + ni*16] = hh[mi][ni][r] + cr[mi][ni][r]*(1.f/2048.f);
      }
    }
  }
}

// ---------------- layer-2 grouped up-GEMM: bf16 MFMA ----------------
__global__ __launch_bounds__(256) void up_kernel(const u16* __restrict__ hf,
    const u16* __restrict__ w0T, const u16* __restrict__ w1T,
    const int* __restrict__ tok_of, const int* __restrict__ offs, const int* __restrict__ counts,
    u16* __restrict__ hid){
  int bx = blockIdx.x;
  int e  = bx >> 9;
  int mt = (bx >> 3) & 63;
  int nt = bx & 7;
  int base = offs[e], cnt = counts[e];
  int row0 = mt << 7;
  if (row0 >= cnt) return;
  __shared__ __align__(16) u16 Al[2][4096], B0l[2][4096], B1l[2][4096];
  int t = threadIdx.x;
  int rq0 = t >> 2, k8 = t & 3;
  int tok0, tok1;
  { int s0 = base + row0 + rq0;      s0 = s0 < NSLOT_ ? s0 : NSLOT_-1; tok0 = tok_of[s0]; }
  { int s1 = base + row0 + 64 + rq0; s1 = s1 < NSLOT_ ? s1 : NSLOT_-1; tok1 = tok_of[s1]; }
  size_t bcol = (size_t)(e*1024 + nt*128);
  f32x4 acc0[4][4], acc1[4][4];
  #pragma unroll
  for (int i = 0; i < 4; ++i)
    #pragma unroll
    for (int j = 0; j < 4; ++j)
      #pragma unroll
      for (int r = 0; r < 4; ++r){ acc0[i][j][r] = 0.f; acc1[i][j][r] = 0.f; }

#define STAGE_UP(bufi, kc) do{ int kk8 = (kc) + (k8<<3); \
    gl_lds16(hf + ((size_t)tok0<<9) + kk8,        &Al[bufi][t*8]); \
    gl_lds16(hf + ((size_t)tok1<<9) + kk8,        &Al[bufi][2048 + t*8]); \
    gl_lds16(w0T + (bcol + rq0)*512 + kk8,        &B0l[bufi][t*8]); \
    gl_lds16(w0T + (bcol + 64 + rq0)*512 + kk8,   &B0l[bufi][2048 + t*8]); \
    gl_lds16(w1T + (bcol + rq0)*512 + kk8,        &B1l[bufi][t*8]); \
    gl_lds16(w1T + (bcol + 64 + rq0)*512 + kk8,   &B1l[bufi][2048 + t*8]); \
  }while(0)

  int l = t & 63, wid = t >> 6, wm = wid >> 1, wn = wid & 1;
  int lr = l & 15, lk = (l >> 4) << 3;
  STAGE_UP(0, 0);
  for (int ks = 0; ks < 16; ++ks){
    int cur = ks & 1;
    __syncthreads();
    if (ks < 15) STAGE_UP(cur^1, (ks+1)*32);
    bf16x8 av[4], b0[4], b1[4];
    #pragma unroll
    for (int mi = 0; mi < 4; ++mi) av[mi] = *(const bf16x8*)&Al[cur][(wm*64 + mi*16 + lr)*32 + lk];
    #pragma unroll
    for (int ni = 0; ni < 4; ++ni){
      b0[ni] = *(const bf16x8*)&B0l[cur][(wn*64 + ni*16 + lr)*32 + lk];
      b1[ni] = *(const bf16x8*)&B1l[cur][(wn*64 + ni*16 + lr)*32 + lk];
    }
    #pragma unroll
    for (int mi = 0; mi < 4; ++mi)
      #pragma unroll
      for (int ni = 0; ni < 4; ++ni){
        acc0[mi][ni] = __builtin_amdgcn_mfma_f32_16x16x32_bf16(av[mi], b0[ni], acc0[mi][ni], 0, 0, 0);
        acc1[mi][ni] = __builtin_amdgcn_mfma_f32_16x16x32_bf16(av[mi], b1[ni], acc1[mi][ni], 0, 0, 0);
      }
  }
#undef STAGE_UP
  #pragma unroll
  for (int mi = 0; mi < 4; ++mi){
    int rbase = row0 + wm*64 + mi*16 + ((l >> 4) << 2);
    #pragma unroll
    for (int r = 0; r < 4; ++r){
      int rr = rbase + r;
      if (rr < cnt){
        size_t srow = (size_t)(base + rr) << 10;
        int cb = nt*128 + wn*64 + lr;
        #pragma unroll
        for (int ni = 0; ni < 4; ++ni){
          float u0 = acc0[mi][ni][r];
          float u1 = acc1[mi][ni][r];
          u0 = u0 > 0.f ? u0 : 0.f;
          hid[srow + cb + ni*16] = f2bf(u0*u1);
        }
      }
    }
  }
}

// ---------------- layer-2 grouped down-GEMM: bf16 MFMA ----------------
__global__ __launch_bounds__(256) void down_kernel(const u16* __restrict__ hid,
    const u16* __restrict__ woT, const int* __restrict__ offs, const int* __restrict__ counts,
    float* __restrict__ eo){
  int bx = blockIdx.x;
  int e  = bx >> 8;
  int mt = (bx >> 2) & 63;
  int nt = bx & 3;
  int base = offs[e], cnt = counts[e];
  int row0 = mt << 7;
  if (row0 >= cnt) return;
  __shared__ __align__(16) u16 Al[2][4096], Bl[2][4096];
  int t = threadIdx.x;
  int rq = t >> 2, k8 = t & 3;
  int r0 = base + row0 + rq;      r0 = r0 < NSLOT_ ? r0 : NSLOT_-1;
  int r1 = base + row0 + 64 + rq; r1 = r1 < NSLOT_ ? r1 : NSLOT_-1;
  size_t bcol = (size_t)(e*512 + nt*128);
  f32x4 acc[4][4];
  #pragma unroll
  for (int i = 0; i < 4; ++i)
    #pragma unroll
    for (int j = 0; j < 4; ++j)
      #pragma unroll
      for (int r = 0; r < 4; ++r) acc[i][j][r] = 0.f;

#define STAGE_DN(bufi, kc) do{ int kk8 = (kc) + (k8<<3); \
    gl_lds16(hid + ((size_t)r0<<10) + kk8,         &Al[bufi][t*8]); \
    gl_lds16(hid + ((size_t)r1<<10) + kk8,         &Al[bufi][2048 + t*8]); \
    gl_lds16(woT + (bcol + rq)*1024 + kk8,         &Bl[bufi][t*8]); \
    gl_lds16(woT + (bcol + 64 + rq)*1024 + kk8,    &Bl[bufi][2048 + t*8]); \
  }while(0)

  int l = t & 63, wid = t >> 6, wm = wid >> 1, wn = wid & 1;
  int lr = l & 15, lk = (l >> 4) << 3;
  STAGE_DN(0, 0);
  for (int ks = 0; ks < 32; ++ks){
    int cur = ks & 1;
    __syncthreads();
    if (ks < 31) STAGE_DN(cur^1, (ks+1)*32);
    bf16x8 av[4], bv[4];
    #pragma unroll
    for (int mi = 0; mi < 4; ++mi) av[mi] = *(const bf16x8*)&Al[cur][(wm*64 + mi*16 + lr)*32 + lk];
    #pragma unroll
    for (int ni = 0; ni < 4; ++ni) bv[ni] = *(const bf16x8*)&Bl[cur][(wn*64 + ni*16 + lr)*32 + lk];
    #pragma unroll
    for (int mi = 0; mi < 4; ++mi)
      #pragma unroll
      for (int ni = 0; ni < 4; ++ni)
        acc[mi][ni] = __builtin_amdgcn_mfma_f32_16x16x32_bf16(av[mi], bv[ni], acc[mi][ni], 0, 0, 0);
  }
#undef STAGE_DN
  #pragma unroll
  for (int mi = 0; mi < 4; ++mi){
    int rbase = row0 + wm*64 + mi*16 + ((l >> 4) << 2);
    #pragma unroll
    for (int r = 0; r < 4; ++r){
      int rr = rbase + r;
      if (rr < cnt){
        size_t srow = (size_t)(base + rr) << 9;
        int cb = nt*128 + wn*64 + lr;
        #pragma unroll
        for (int ni = 0; ni < 4; ++ni)
          eo[srow + cb + ni*16] = acc[mi][ni][r];
      }
    }
  }
}

// ---------------- gather + residual ----------------
__global__ __launch_bounds__(128) void gather_kernel(const float* __restrict__ xin,
    const float* __restrict__ eo, const int* __restrict__ slot_of, const float* __restrict__ wv,
    float* __restrict__ out){
  int n = blockIdx.x, t = threadIdx.x;
  int s0 = slot_of[2*n], s1 = slot_of[2*n+1];
  double w0 = wv[2*n], w1 = wv[2*n+1];
  float4 xi = *(const float4*)&xin[((size_t)n << 9) + t*4];
  float4 e0 = *(const float4*)&eo[((size_t)s0 << 9) + t*4];
  float4 e1 = *(const float4*)&eo[((size_t)s1 << 9) + t*4];
  float4 o;
  o.x = (float)((double)xi.x + w0*(double)e0.x + w1*(double)e1.x);
  o.y = (float)((double)xi.y + w0*(double)e0.y + w1*(double)e1.y);
  o.z = (float)((double)xi.z + w0*(double)e0.z + w1*(double)e1.z);
  o.w = (float)((double)xi.w + w0*(double)e0.w + w1*(double)e1.w);
  *(float4*)&out[((size_t)n << 9) + t*4] = o;
}

extern "C" void kernel_launch(void* const* d_in, const int* in_sizes, int n_in,
                              void* d_out, int out_size, void* d_ws, size_t ws_size,
                              hipStream_t stream) {
  (void)in_sizes; (void)n_in; (void)out_size; (void)ws_size;
  const float* x0   = (const float*)d_in[0];
  const int*   sid  = (const int*)  d_in[1];
  const float* ln_g = (const float*)d_in[2];
  const float* ln_b = (const float*)d_in[3];
  const float* semb = (const float*)d_in[4];
  const float* h1w  = (const float*)d_in[5];
  const float* h1b  = (const float*)d_in[6];
  const float* h2w  = (const float*)d_in[7];
  const float* h2b  = (const float*)d_in[8];
  const float* s1w  = (const float*)d_in[9];
  const float* s1b  = (const float*)d_in[10];
  const float* s2w  = (const float*)d_in[11];
  const float* s2b  = (const float*)d_in[12];
  const float* g1w  = (const float*)d_in[13];
  const float* g1b  = (const float*)d_in[14];
  const float* g2w  = (const float*)d_in[15];
  const float* g2b  = (const float*)d_in[16];
  const float* wi0  = (const float*)d_in[17];
  const float* wi1  = (const float*)d_in[18];
  const float* wo   = (const float*)d_in[19];

  char* W = (char*)d_ws;
  float*  h      = (float*)(W + 0);                     // 16 MB
  u16*    hfh    = (u16*)  (W + 16777216ULL);           //  8 MB
  u16*    hfl    = (u16*)  (W + 25165824ULL);           //  8 MB
  float*  eo32   = (float*)(W + 0);                     // 32 MB overlay (h+hfh+hfl)
  u16*    hfb    = (u16*)  (W + 33554432ULL);           //  8 MB
  u16*    hid16h = (u16*)  (W + 41943040ULL);           // 32 MB (also hidb layer-2)
  u16*    hidb   = (u16*)  (W + 41943040ULL);
  u16*    hid16l = (u16*)  (W + 75497472ULL);           // 32 MB
  u16*    w0Th   = (u16*)  (W + 109051904ULL);          //  8 MB each
  u16*    w0Tl   = (u16*)  (W + 117440512ULL);
  u16*    w1Th   = (u16*)  (W + 125829120ULL);
  u16*    w1Tl   = (u16*)  (W + 134217728ULL);
  u16*    woTh   = (u16*)  (W + 142606336ULL);
  u16*    woTl   = (u16*)  (W + 150994944ULL);
  u16*    wi0T   = (u16*)  (W + 159383552ULL);          // bf16 layer-2
  u16*    wi1T   = (u16*)  (W + 167772160ULL);
  u16*    woT    = (u16*)  (W + 176160768ULL);
  double* cs     = (double*)(W + 184549376ULL);
  double* cq     = (double*)(W + 184582144ULL);
  double* a64    = (double*)(W + 184614912ULL);
  double* c64    = (double*)(W + 184647680ULL);
  int*    idxa   = (int*)   (W + 184680448ULL);
  float*  warr   = (float*) (W + 184745984ULL);
  int*    tok_of = (int*)   (W + 184811520ULL);
  int*    slot_of= (int*)   (W + 184877056ULL);
  int*    counts = (int*)   (W + 184942592ULL);
  int*    cur    = counts + 8;
  int*    offs   = counts + 16;

  cvtT<<<4096, 256, 0, stream>>>(wi0, wi0T, 512, 1024);
  cvtT<<<4096, 256, 0, stream>>>(wi1, wi1T, 512, 1024);
  cvtT<<<4096, 256, 0, stream>>>(wo,  woT,  1024, 512);
  cvtT16<<<4096, 256, 0, stream>>>(wi0, w0Th, w0Tl, 512, 1024);
  cvtT16<<<4096, 256, 0, stream>>>(wi1, w1Th, w1Tl, 512, 1024);
  cvtT16<<<4096, 256, 0, stream>>>(wo,  woTh, woTl, 1024, 512);

  for (int l = 0; l < 2; ++l){
    const float* xin = l ? (const float*)d_out : x0;
    ln_kernel<<<8192, 256, 0, stream>>>(xin, ln_g + l*512, ln_b + l*512, h);
    colstats<<<64, 256, 0, stream>>>(h, cs, cq);
    subj_kernel<<<1, 256, 0, stream>>>(sid, semb, h1w, h1b, h2w, h2b, s1w, s1b, s2w, s2b,
                                       cs, cq, a64, c64, l);
    hfcast<<<2048, 256, 0, stream>>>(h, a64, c64, hfh, hfl, hfb);
    zero_counts<<<1, 64, 0, stream>>>(counts);
    gate_kernel<<<256, 256, 0, stream>>>(h, a64, c64, g1w, g1b, g2w, g2b, idxa, warr, counts);
    offsets_kernel<<<1, 1, 0, stream>>>(counts, offs, cur);
    scatter_kernel<<<32, 256, 0, stream>>>(idxa, offs, cur, tok_of, slot_of);
    if (l == 0){
      up1_kernel<<<8192, 256, 0, stream>>>(hfh, hfl, w0Th, w0Tl, w1Th, w1Tl,
                                           tok_of, offs, counts, hid16h, hid16l);
      down1_kernel<<<4096, 256, 0, stream>>>(hid16h, hid16l, woTh, woTl, offs, counts, eo32);
    } else {
      up_kernel<<<4096, 256, 0, stream>>>(hfb, wi0T, wi1T, tok_of, offs, counts, hidb);
      down_kernel<<<2048, 256, 0, stream>>>(hidb, woT, offs, counts, eo32);
    }
    gather_kernel<<<8192, 128, 0, stream>>>(xin, eo32, slot_of, warr, (float*)d_out);
  }
}

// Round 4
// 1171.495 us; speedup vs baseline: 2.6362x; 1.0800x over previous
//
#include <hip/hip_runtime.h>

typedef unsigned short u16;
typedef unsigned int   u32;
typedef _Float16       f16;
typedef __attribute__((ext_vector_type(8))) _Float16 f16x8;
typedef __attribute__((ext_vector_type(4))) float    f32x4;
typedef __attribute__((ext_vector_type(4))) double   dbl4;

#define NSLOT_ 16384   // N * K = 8192 * 2

__device__ __forceinline__ u16 f16bits(f16 h){ union{f16 f; u16 u;} x; x.f = h; return x.u; }

__device__ __forceinline__ void gl_lds16(const void* gptr, void* lptr){
  __builtin_amdgcn_global_load_lds((const __attribute__((address_space(1))) u32*)gptr,
                                   (__attribute__((address_space(3))) u32*)lptr, 16, 0, 0);
}

// ---------------- per-token LayerNorm over D=512 (f64 math, f32 out) ----------------
__global__ __launch_bounds__(256) void ln_kernel(const float* __restrict__ x,
    const float* __restrict__ g, const float* __restrict__ bb, float* __restrict__ h){
  int n = blockIdx.x, t = threadIdx.x;
  const float* xr = x + ((size_t)n << 9);
  float2 v = *(const float2*)&xr[t*2];
  double vx = v.x, vy = v.y;
  double s = vx + vy;
  double q = vx*vx + vy*vy;
  #pragma unroll
  for (int o = 32; o > 0; o >>= 1){ s += __shfl_down(s, o, 64); q += __shfl_down(q, o, 64); }
  __shared__ double ls[4], lq_[4];
  __shared__ double sm, sv;
  int wid = t >> 6, lane = t & 63;
  if (lane == 0){ ls[wid] = s; lq_[wid] = q; }
  __syncthreads();
  if (t == 0){
    double S = ls[0]+ls[1]+ls[2]+ls[3], Q = lq_[0]+lq_[1]+lq_[2]+lq_[3];
    double mean = S * (1.0/512.0);
    double var  = Q * (1.0/512.0) - mean*mean;
    sm = mean; sv = 1.0/sqrt(var + 1e-5);
  }
  __syncthreads();
  double mean = sm, inv = sv;
  int d = t*2;
  float2 o;
  o.x = (float)((vx - mean)*inv*(double)g[d]   + (double)bb[d]);
  o.y = (float)((vy - mean)*inv*(double)g[d+1] + (double)bb[d+1]);
  *(float2*)&h[((size_t)n<<9) + d] = o;
}

// ---------------- column stats over T per (b,d), f64 accum from f32 h ----------------
__global__ __launch_bounds__(256) void colstats(const float* __restrict__ h,
    double* __restrict__ cs, double* __restrict__ cq){
  int bid = blockIdx.x;
  int b = bid >> 3, ch = bid & 7;
  int t = threadIdx.x;
  int col = ch*64 + (t & 63);
  int tp = t >> 6;
  const float* base = h + ((size_t)b << 19);
  double s = 0.0, q = 0.0;
  for (int tt = tp; tt < 1024; tt += 4){
    double v = (double)base[((size_t)tt << 9) + col];
    s += v; q += v*v;
  }
  __shared__ double ls[4][64], lq[4][64];
  ls[tp][t & 63] = s; lq[tp][t & 63] = q;
  __syncthreads();
  if (tp == 0){
    double S = ls[0][t]+ls[1][t]+ls[2][t]+ls[3][t];
    double Q = lq[0][t]+lq[1][t]+lq[2][t]+lq[3][t];
    cs[(b<<9)+col] = S; cq[(b<<9)+col] = Q;
  }
}

// ---------------- subject MLP -> per-(b,d) affine a,c (f64), one block per b ----------------
__global__ __launch_bounds__(256) void subj_kernel(const int* __restrict__ sid,
    const float* __restrict__ semb,
    const float* __restrict__ h1w, const float* __restrict__ h1b,
    const float* __restrict__ h2w, const float* __restrict__ h2b,
    const float* __restrict__ s1w, const float* __restrict__ s1b,
    const float* __restrict__ s2w, const float* __restrict__ s2b,
    const double* __restrict__ cs, const double* __restrict__ cq,
    double* __restrict__ a64, double* __restrict__ c64, int l){
  __shared__ double ev[64], hid1[128], hh[128], sh[64], sp[1024];
  int t = threadIdx.x;
  int b = blockIdx.x;
  int s = sid[b];
  if (t < 64) ev[t] = (double)semb[l*4096 + s*64 + t];
  __syncthreads();
  if (t < 128){
    double acc = (double)h1b[l*128 + t];
    for (int i = 0; i < 64; ++i) acc += ev[i]*(double)h1w[l*8192 + i*128 + t];
    hid1[t] = acc > 0.0 ? acc : 0.0;
  }
  __syncthreads();
  if (t < 128){
    double acc = (double)h2b[l*128 + t];
    for (int i = 0; i < 128; ++i) acc += hid1[i]*(double)h2w[l*16384 + i*128 + t];
    hh[t] = acc;
  }
  __syncthreads();
  if (t < 64){
    double acc = (double)s1b[l*64 + t];
    for (int i = 0; i < 128; ++i) acc += hh[i]*(double)s1w[l*8192 + i*64 + t];
    sh[t] = acc > 0.0 ? acc : 0.0;
  }
  __syncthreads();
  for (int m = t; m < 1024; m += 256){
    double acc = (double)s2b[l*1024 + m];
    for (int j = 0; j < 64; ++j) acc += sh[j]*(double)s2w[l*65536 + j*1024 + m];
    sp[m] = acc;
  }
  __syncthreads();
  for (int d = t; d < 512; d += 256){
    double mu  = cs[(b<<9)+d] * (1.0/1024.0);
    double var = cq[(b<<9)+d] * (1.0/1024.0) - mu*mu;
    double inv = 1.0/sqrt(var + 1e-8);
    double spv = sp[d];
    double gamma = (spv > 30.0 ? spv : log1p(exp(spv))) + 1e-8;
    double beta  = sp[512 + d];
    double A = gamma * inv;
    a64[(b<<9)+d] = A;
    c64[(b<<9)+d] = beta - mu*A;
  }
}

// ---------------- hf = h*a + c -> fp16 hi/lo' (lo scaled 2^11) ----------------
__global__ __launch_bounds__(256) void hfcast(const float* __restrict__ h,
    const double* __restrict__ a64, const double* __restrict__ c64,
    u16* __restrict__ hfh, u16* __restrict__ hfl){
  size_t i0 = ((size_t)blockIdx.x*256 + threadIdx.x) * 8;
  int n = (int)(i0 >> 9);
  int d0 = (int)(i0 & 511);
  int b = n >> 10;
  float4 x0 = *(const float4*)&h[i0];
  float4 x1 = *(const float4*)&h[i0 + 4];
  dbl4 a0 = *(const dbl4*)&a64[(b<<9) + d0];
  dbl4 a1 = *(const dbl4*)&a64[(b<<9) + d0 + 4];
  dbl4 c0 = *(const dbl4*)&c64[(b<<9) + d0];
  dbl4 c1 = *(const dbl4*)&c64[(b<<9) + d0 + 4];
  float f[8];
  f[0] = (float)((double)x0.x*a0[0] + c0[0]);
  f[1] = (float)((double)x0.y*a0[1] + c0[1]);
  f[2] = (float)((double)x0.z*a0[2] + c0[2]);
  f[3] = (float)((double)x0.w*a0[3] + c0[3]);
  f[4] = (float)((double)x1.x*a1[0] + c1[0]);
  f[5] = (float)((double)x1.y*a1[1] + c1[1]);
  f[6] = (float)((double)x1.z*a1[2] + c1[2]);
  f[7] = (float)((double)x1.w*a1[3] + c1[3]);
  ushort4 oh0, oh1, ol0, ol1;
  u16 vh[8], vl[8];
  #pragma unroll
  for (int j = 0; j < 8; ++j){
    f16 hi = (f16)f[j];
    float rem = (f[j] - (float)hi) * 2048.f;
    f16 lo = (f16)rem;
    vh[j] = f16bits(hi); vl[j] = f16bits(lo);
  }
  oh0.x=vh[0]; oh0.y=vh[1]; oh0.z=vh[2]; oh0.w=vh[3];
  oh1.x=vh[4]; oh1.y=vh[5]; oh1.z=vh[6]; oh1.w=vh[7];
  ol0.x=vl[0]; ol0.y=vl[1]; ol0.z=vl[2]; ol0.w=vl[3];
  ol1.x=vl[4]; ol1.y=vl[5]; ol1.z=vl[6]; ol1.w=vl[7];
  *(ushort4*)&hfh[i0]   = oh0;
  *(ushort4*)&hfh[i0+4] = oh1;
  *(ushort4*)&hfl[i0]   = ol0;
  *(ushort4*)&hfl[i0+4] = ol1;
}

__global__ void zero_counts(int* __restrict__ counts){
  if (threadIdx.x < 8) counts[threadIdx.x] = 0;
}

// ---------------- gating: fp16-split MFMA (f32 accum) + f64 finish, top-2 ----------------
// grid 512 blocks (16 tokens each), 256 threads (4 waves; wave w owns cols w*64..+63)
__global__ __launch_bounds__(256) void gate2_kernel(const u16* __restrict__ hfh,
    const u16* __restrict__ hfl, const u16* __restrict__ g1Th, const u16* __restrict__ g1Tl,
    const float* __restrict__ g1b, const float* __restrict__ g2w, const float* __restrict__ g2b,
    int* __restrict__ idxo, float* __restrict__ wo_, int* __restrict__ counts){
  __shared__ double hid_s[16][258];
  __shared__ double lg[16*8];
  __shared__ int lcnt[8];
  int t = threadIdx.x, w = t >> 6, l = t & 63;
  int tok0 = blockIdx.x << 4;
  if (t < 8) lcnt[t] = 0;
  int lr = l & 15, lks = l >> 4;
  const u16* ahp = hfh + ((size_t)(tok0 + lr) << 9) + lks*8;
  const u16* alp = hfl + ((size_t)(tok0 + lr) << 9) + lks*8;
  const u16* bhp[4]; const u16* blp[4];
  #pragma unroll
  for (int nf = 0; nf < 4; ++nf){
    int col = w*64 + nf*16 + lr;
    bhp[nf] = g1Th + ((size_t)col << 9) + lks*8;
    blp[nf] = g1Tl + ((size_t)col << 9) + lks*8;
  }
  f32x4 hh[4], cr[4];
  #pragma unroll
  for (int nf = 0; nf < 4; ++nf)
    #pragma unroll
    for (int r = 0; r < 4; ++r){ hh[nf][r] = 0.f; cr[nf][r] = 0.f; }
  for (int kc = 0; kc < 512; kc += 32){
    f16x8 ah = *(const f16x8*)(ahp + kc);
    f16x8 al = *(const f16x8*)(alp + kc);
    #pragma unroll
    for (int nf = 0; nf < 4; ++nf){
      f16x8 bh = *(const f16x8*)(bhp[nf] + kc);
      f16x8 bl = *(const f16x8*)(blp[nf] + kc);
      hh[nf] = __builtin_amdgcn_mfma_f32_16x16x32_f16(ah, bh, hh[nf], 0, 0, 0);
      cr[nf] = __builtin_amdgcn_mfma_f32_16x16x32_f16(ah, bl, cr[nf], 0, 0, 0);
      cr[nf] = __builtin_amdgcn_mfma_f32_16x16x32_f16(al, bh, cr[nf], 0, 0, 0);
    }
  }
  #pragma unroll
  for (int nf = 0; nf < 4; ++nf){
    int col = w*64 + nf*16 + lr;
    double gb = (double)g1b[col];
    #pragma unroll
    for (int r = 0; r < 4; ++r){
      int row = lks*4 + r;
      double v = (double)hh[nf][r] + (double)cr[nf][r]*(1.0/2048.0) + gb;
      hid_s[row][col] = v > 0.0 ? v : 0.0;
    }
  }
  __syncthreads();
  if (t < 128){
    int tok = t >> 3, e = t & 7;
    double la = (double)g2b[e];
    for (int k = 0; k < 256; ++k) la += hid_s[tok][k]*(double)g2w[(k<<3)+e];
    lg[(tok<<3)+e] = la;
  }
  __syncthreads();
  if (t < 16){
    double l0[8];
    #pragma unroll
    for (int e = 0; e < 8; ++e) l0[e] = lg[(t<<3)+e];
    double m = l0[0];
    #pragma unroll
    for (int e = 1; e < 8; ++e) m = fmax(m, l0[e]);
    double p[8]; double s = 0.0;
    #pragma unroll
    for (int e = 0; e < 8; ++e){ p[e] = exp(l0[e]-m); s += p[e]; }
    double b1 = -1e300, b2 = -1e300; int i1 = 0, i2 = 1;
    #pragma unroll
    for (int e = 0; e < 8; ++e){
      double v = l0[e];
      if (v > b1){ b2 = b1; i2 = i1; b1 = v; i1 = e; }
      else if (v > b2){ b2 = v; i2 = e; }
    }
    double pr1 = p[i1]/s, pr2 = p[i2]/s;
    double den = pr1 + pr2 + 1e-8;
    int n = tok0 + t;
    idxo[2*n] = i1; idxo[2*n+1] = i2;
    wo_[2*n] = (float)(pr1/den); wo_[2*n+1] = (float)(pr2/den);
    atomicAdd(&lcnt[i1], 1); atomicAdd(&lcnt[i2], 1);
  }
  __syncthreads();
  if (t < 8) atomicAdd(&counts[t], lcnt[t]);
}

__global__ void offsets_kernel(const int* __restrict__ counts, int* __restrict__ offs,
                               int* __restrict__ cur){
  if (threadIdx.x == 0 && blockIdx.x == 0){
    int run = 0;
    for (int e = 0; e < 8; ++e){ offs[e] = run; run += counts[e]; cur[e] = 0; }
  }
}

__global__ __launch_bounds__(256) void scatter_kernel(const int* __restrict__ idx,
    const int* __restrict__ offs, int* __restrict__ cur,
    int* __restrict__ tok_of, int* __restrict__ slot_of){
  __shared__ int lcnt[8], lbase[8];
  int t = threadIdx.x;
  int n = blockIdx.x*256 + t;
  if (t < 8) lcnt[t] = 0;
  __syncthreads();
  int e0 = idx[2*n], e1 = idx[2*n+1];
  int p0 = atomicAdd(&lcnt[e0], 1);
  int p1 = atomicAdd(&lcnt[e1], 1);
  __syncthreads();
  if (t < 8) lbase[t] = atomicAdd(&cur[t], lcnt[t]);
  __syncthreads();
  int s0 = offs[e0] + lbase[e0] + p0;
  int s1 = offs[e1] + lbase[e1] + p1;
  tok_of[s0] = n; tok_of[s1] = n;
  slot_of[2*n] = s0; slot_of[2*n+1] = s1;
}

// ---------------- weight transpose + fp16 hi/lo' split: [E][R][C] -> [E][C][R] ----------------
__global__ __launch_bounds__(256) void cvtT16(const float* __restrict__ src,
    u16* __restrict__ dh, u16* __restrict__ dl, int R, int C){
  int bx = blockIdx.x;
  int tilesC = C >> 5, tilesR = R >> 5;
  int e = bx / (tilesR*tilesC);
  int rem = bx % (tilesR*tilesC);
  int rt = rem / tilesC, ct = rem % tilesC;
  __shared__ float tile[32][33];
  int t = threadIdx.x;
  int j = t & 31, i0 = t >> 5;
  const float* s = src + (size_t)e*R*C + (size_t)(rt*32)*C + ct*32;
  for (int ii = i0; ii < 32; ii += 8) tile[ii][j] = s[(size_t)ii*C + j];
  __syncthreads();
  size_t ob = (size_t)e*R*C + (size_t)(ct*32)*R + rt*32;
  for (int ii = i0; ii < 32; ii += 8){
    float v = tile[j][ii];
    f16 hi = (f16)v;
    float rem2 = (v - (float)hi) * 2048.f;
    f16 lo = (f16)rem2;
    dh[ob + (size_t)ii*R + j] = f16bits(hi);
    dl[ob + (size_t)ii*R + j] = f16bits(lo);
  }
}

// ---------------- layer-1 up-GEMM: fp16-split, 64r x 64c blocks ----------------
// grid: e(8) x mt(256; 64 rows) x nt(16; 64 cols). A-hi/B-hi via LDS (seg-major,
// padded: conflict-free), A-lo/B-lo direct global->reg.
__global__ __launch_bounds__(256) void up1_kernel(const u16* __restrict__ hfh,
    const u16* __restrict__ hfl,
    const u16* __restrict__ w0h, const u16* __restrict__ w0l,
    const u16* __restrict__ w1h, const u16* __restrict__ w1l,
    const int* __restrict__ tok_of, const int* __restrict__ offs, const int* __restrict__ counts,
    u16* __restrict__ hidh, u16* __restrict__ hidl){
  int bx = blockIdx.x;
  int e  = bx >> 12;
  int mt = (bx >> 4) & 255;
  int nt = bx & 15;
  int base = offs[e], cnt = counts[e];
  int row0 = mt << 6;
  if (row0 >= cnt) return;
  __shared__ __align__(16) u16 Ah[2][2176];   // 4 segs x (64*8 + 32 pad)
  __shared__ __align__(16) u16 B0[2][2176];
  __shared__ __align__(16) u16 B1[2][2176];
  int t = threadIdx.x, w = t >> 6, l = t & 63;
  int wm = w >> 1, wn = w & 1;
  int lr = l & 15, lks = l >> 4;
  int stok; { int ss = base + row0 + l; ss = ss < NSLOT_ ? ss : NSLOT_-1; stok = tok_of[ss]; }
  const u16* sA  = hfh + ((size_t)stok << 9) + w*8;
  size_t bcol = (size_t)(e*1024 + nt*64);
  const u16* sB0 = w0h + ((bcol + l) << 9) + w*8;
  const u16* sB1 = w1h + ((bcol + l) << 9) + w*8;
  int sdst = w*544 + l*8;
  int tokM[2];
  #pragma unroll
  for (int mi = 0; mi < 2; ++mi){
    int ss = base + row0 + wm*32 + mi*16 + lr; ss = ss < NSLOT_ ? ss : NSLOT_-1;
    tokM[mi] = tok_of[ss];
  }
  const u16* pal[2];
  #pragma unroll
  for (int mi = 0; mi < 2; ++mi) pal[mi] = hfl + ((size_t)tokM[mi] << 9) + lks*8;
  const u16* pbl0[2]; const u16* pbl1[2];
  #pragma unroll
  for (int ni = 0; ni < 2; ++ni){
    size_t ci = (bcol + wn*32 + ni*16 + lr) << 9;
    pbl0[ni] = w0l + ci + lks*8;
    pbl1[ni] = w1l + ci + lks*8;
  }
  f32x4 hh0[2][2], cr0[2][2], hh1[2][2], cr1[2][2];
  #pragma unroll
  for (int i = 0; i < 2; ++i)
    #pragma unroll
    for (int j = 0; j < 2; ++j)
      #pragma unroll
      for (int r = 0; r < 4; ++r){ hh0[i][j][r]=0.f; cr0[i][j][r]=0.f; hh1[i][j][r]=0.f; cr1[i][j][r]=0.f; }
#define STG_U(buf, kc) do{ \
    gl_lds16(sA  + (kc), &Ah[buf][sdst]); \
    gl_lds16(sB0 + (kc), &B0[buf][sdst]); \
    gl_lds16(sB1 + (kc), &B1[buf][sdst]); }while(0)
  STG_U(0, 0);
  for (int ks = 0; ks < 16; ++ks){
    int cur = ks & 1, kc = ks*32;
    __syncthreads();
    if (ks < 15) STG_U(cur^1, kc + 32);
    f16x8 al[2], bl0[2], bl1[2];
    #pragma unroll
    for (int mi = 0; mi < 2; ++mi) al[mi] = *(const f16x8*)(pal[mi] + kc);
    #pragma unroll
    for (int ni = 0; ni < 2; ++ni){
      bl0[ni] = *(const f16x8*)(pbl0[ni] + kc);
      bl1[ni] = *(const f16x8*)(pbl1[ni] + kc);
    }
    f16x8 ah[2], bh0[2], bh1[2];
    #pragma unroll
    for (int mi = 0; mi < 2; ++mi) ah[mi] = *(const f16x8*)&Ah[cur][lks*544 + (wm*32 + mi*16 + lr)*8];
    #pragma unroll
    for (int ni = 0; ni < 2; ++ni){
      bh0[ni] = *(const f16x8*)&B0[cur][lks*544 + (wn*32 + ni*16 + lr)*8];
      bh1[ni] = *(const f16x8*)&B1[cur][lks*544 + (wn*32 + ni*16 + lr)*8];
    }
    #pragma unroll
    for (int mi = 0; mi < 2; ++mi)
      #pragma unroll
      for (int ni = 0; ni < 2; ++ni){
        hh0[mi][ni] = __builtin_amdgcn_mfma_f32_16x16x32_f16(ah[mi], bh0[ni], hh0[mi][ni], 0, 0, 0);
        hh1[mi][ni] = __builtin_amdgcn_mfma_f32_16x16x32_f16(ah[mi], bh1[ni], hh1[mi][ni], 0, 0, 0);
        cr0[mi][ni] = __builtin_amdgcn_mfma_f32_16x16x32_f16(ah[mi], bl0[ni], cr0[mi][ni], 0, 0, 0);
        cr0[mi][ni] = __builtin_amdgcn_mfma_f32_16x16x32_f16(al[mi], bh0[ni], cr0[mi][ni], 0, 0, 0);
        cr1[mi][ni] = __builtin_amdgcn_mfma_f32_16x16x32_f16(ah[mi], bl1[ni], cr1[mi][ni], 0, 0, 0);
        cr1[mi][ni] = __builtin_amdgcn_mfma_f32_16x16x32_f16(al[mi], bh1[ni], cr1[mi][ni], 0, 0, 0);
      }
  }
#undef STG_U
  #pragma unroll
  for (int mi = 0; mi < 2; ++mi){
    int rb = row0 + wm*32 + mi*16 + lks*4;
    #pragma unroll
    for (int r = 0; r < 4; ++r){
      int rr = rb + r;
      if (rr < cnt){
        size_t orow = ((size_t)(base + rr) << 10) + nt*64;
        #pragma unroll
        for (int ni = 0; ni < 2; ++ni){
          int col = wn*32 + ni*16 + lr;
          float u0 = hh0[mi][ni][r] + cr0[mi][ni][r]*(1.f/2048.f);
          float u1 = hh1[mi][ni][r] + cr1[mi][ni][r]*(1.f/2048.f);
          u0 = u0 > 0.f ? u0 : 0.f;
          float v = u0*u1;
          f16 vh = (f16)v;
          float rem = (v - (float)vh)*2048.f;
          hidh[orow + col] = f16bits(vh);
          hidl[orow + col] = f16bits((f16)rem);
        }
      }
    }
  }
}

// ---------------- layer-1 down-GEMM: fp16-split, 128r x 64c ----------------
// grid: e(8) x mt(128; 128 rows) x nt(8; 64 cols)
__global__ __launch_bounds__(256) void down1_kernel(const u16* __restrict__ hidh,
    const u16* __restrict__ hidl, const u16* __restrict__ wdh, const u16* __restrict__ wdl,
    const int* __restrict__ offs, const int* __restrict__ counts, float* __restrict__ eo){
  int bx = blockIdx.x;
  int e  = bx >> 10;
  int mt = (bx >> 3) & 127;
  int nt = bx & 7;
  int base = offs[e], cnt = counts[e];
  int row0 = mt << 7;
  if (row0 >= cnt) return;
  __shared__ __align__(16) u16 Ah[2][4224];   // 4 segs x (128*8 + 32 pad)
  __shared__ __align__(16) u16 Bw[2][2176];
  int t = threadIdx.x, w = t >> 6, l = t & 63;
  int wm = w >> 1, wn = w & 1;
  int lr = l & 15, lks = l >> 4;
  int s0 = base + row0 + l;       s0 = s0 < NSLOT_ ? s0 : NSLOT_-1;
  int s1 = base + row0 + 64 + l;  s1 = s1 < NSLOT_ ? s1 : NSLOT_-1;
  const u16* sA0 = hidh + ((size_t)s0 << 10) + w*8;
  const u16* sA1 = hidh + ((size_t)s1 << 10) + w*8;
  size_t bcol = (size_t)(e*512 + nt*64);
  const u16* sB = wdh + ((bcol + l) << 10) + w*8;
  int dA0 = w*1056 + l*8, dA1 = w*1056 + 512 + l*8, dB = w*544 + l*8;
  const u16* pal[4];
  #pragma unroll
  for (int mi = 0; mi < 4; ++mi){
    int ss = base + row0 + wm*64 + mi*16 + lr; ss = ss < NSLOT_ ? ss : NSLOT_-1;
    pal[mi] = hidl + ((size_t)ss << 10) + lks*8;
  }
  const u16* pbl[2];
  #pragma unroll
  for (int ni = 0; ni < 2; ++ni) pbl[ni] = wdl + ((bcol + wn*32 + ni*16 + lr) << 10) + lks*8;
  f32x4 hh[4][2], cr[4][2];
  #pragma unroll
  for (int i = 0; i < 4; ++i)
    #pragma unroll
    for (int j = 0; j < 2; ++j)
      #pragma unroll
      for (int r = 0; r < 4; ++r){ hh[i][j][r]=0.f; cr[i][j][r]=0.f; }
#define STG_D(buf, kc) do{ \
    gl_lds16(sA0 + (kc), &Ah[buf][dA0]); \
    gl_lds16(sA1 + (kc), &Ah[buf][dA1]); \
    gl_lds16(sB  + (kc), &Bw[buf][dB]); }while(0)
  STG_D(0, 0);
  for (int ks = 0; ks < 32; ++ks){
    int cur = ks & 1, kc = ks*32;
    __syncthreads();
    if (ks < 31) STG_D(cur^1, kc + 32);
    f16x8 al[4], bl[2], ah[4], bh[2];
    #pragma unroll
    for (int mi = 0; mi < 4; ++mi) al[mi] = *(const f16x8*)(pal[mi] + kc);
    #pragma unroll
    for (int ni = 0; ni < 2; ++ni) bl[ni] = *(const f16x8*)(pbl[ni] + kc);
    #pragma unroll
    for (int mi = 0; mi < 4; ++mi) ah[mi] = *(const f16x8*)&Ah[cur][lks*1056 + (wm*64 + mi*16 + lr)*8];
    #pragma unroll
    for (int ni = 0; ni < 2; ++ni) bh[ni] = *(const f16x8*)&Bw[cur][lks*544 + (wn*32 + ni*16 + lr)*8];
    #pragma unroll
    for (int mi = 0; mi < 4; ++mi)
      #pragma unroll
      for (int ni = 0; ni < 2; ++ni){
        hh[mi][ni] = __builtin_amdgcn_mfma_f32_16x16x32_f16(ah[mi], bh[ni], hh[mi][ni], 0, 0, 0);
        cr[mi][ni] = __builtin_amdgcn_mfma_f32_16x16x32_f16(ah[mi], bl[ni], cr[mi][ni], 0, 0, 0);
        cr[mi][ni] = __builtin_amdgcn_mfma_f32_16x16x32_f16(al[mi], bh[ni], cr[mi][ni], 0, 0, 0);
      }
  }
#undef STG_D
  #pragma unroll
  for (int mi = 0; mi < 4; ++mi){
    int rb = row0 + wm*64 + mi*16 + lks*4;
    #pragma unroll
    for (int r = 0; r < 4; ++r){
      int rr = rb + r;
      if (rr < cnt){
        float* orow = eo + (((size_t)(base + rr)) << 9) + nt*64;
        #pragma unroll
        for (int ni = 0; ni < 2; ++ni)
          orow[wn*32 + ni*16 + lr] = hh[mi][ni][r] + cr[mi][ni][r]*(1.f/2048.f);
      }
    }
  }
}

// ---------------- layer-2 up-GEMM: fp16 hi-only ----------------
__global__ __launch_bounds__(256) void uph_kernel(const u16* __restrict__ hfh,
    const u16* __restrict__ w0h, const u16* __restrict__ w1h,
    const int* __restrict__ tok_of, const int* __restrict__ offs, const int* __restrict__ counts,
    u16* __restrict__ hidh){
  int bx = blockIdx.x;
  int e  = bx >> 12;
  int mt = (bx >> 4) & 255;
  int nt = bx & 15;
  int base = offs[e], cnt = counts[e];
  int row0 = mt << 6;
  if (row0 >= cnt) return;
  __shared__ __align__(16) u16 Ah[2][2176];
  __shared__ __align__(16) u16 B0[2][2176];
  __shared__ __align__(16) u16 B1[2][2176];
  int t = threadIdx.x, w = t >> 6, l = t & 63;
  int wm = w >> 1, wn = w & 1;
  int lr = l & 15, lks = l >> 4;
  int stok; { int ss = base + row0 + l; ss = ss < NSLOT_ ? ss : NSLOT_-1; stok = tok_of[ss]; }
  const u16* sA  = hfh + ((size_t)stok << 9) + w*8;
  size_t bcol = (size_t)(e*1024 + nt*64);
  const u16* sB0 = w0h + ((bcol + l) << 9) + w*8;
  const u16* sB1 = w1h + ((bcol + l) << 9) + w*8;
  int sdst = w*544 + l*8;
  f32x4 hh0[2][2], hh1[2][2];
  #pragma unroll
  for (int i = 0; i < 2; ++i)
    #pragma unroll
    for (int j = 0; j < 2; ++j)
      #pragma unroll
      for (int r = 0; r < 4; ++r){ hh0[i][j][r]=0.f; hh1[i][j][r]=0.f; }
#define STG_UH(buf, kc) do{ \
    gl_lds16(sA  + (kc), &Ah[buf][sdst]); \
    gl_lds16(sB0 + (kc), &B0[buf][sdst]); \
    gl_lds16(sB1 + (kc), &B1[buf][sdst]); }while(0)
  STG_UH(0, 0);
  for (int ks = 0; ks < 16; ++ks){
    int cur = ks & 1, kc = ks*32;
    __syncthreads();
    if (ks < 15) STG_UH(cur^1, kc + 32);
    f16x8 ah[2], bh0[2], bh1[2];
    #pragma unroll
    for (int mi = 0; mi < 2; ++mi) ah[mi] = *(const f16x8*)&Ah[cur][lks*544 + (wm*32 + mi*16 + lr)*8];
    #pragma unroll
    for (int ni = 0; ni < 2; ++ni){
      bh0[ni] = *(const f16x8*)&B0[cur][lks*544 + (wn*32 + ni*16 + lr)*8];
      bh1[ni] = *(const f16x8*)&B1[cur][lks*544 + (wn*32 + ni*16 + lr)*8];
    }
    #pragma unroll
    for (int mi = 0; mi < 2; ++mi)
      #pragma unroll
      for (int ni = 0; ni < 2; ++ni){
        hh0[mi][ni] = __builtin_amdgcn_mfma_f32_16x16x32_f16(ah[mi], bh0[ni], hh0[mi][ni], 0, 0, 0);
        hh1[mi][ni] = __builtin_amdgcn_mfma_f32_16x16x32_f16(ah[mi], bh1[ni], hh1[mi][ni], 0, 0, 0);
      }
  }
#undef STG_UH
  #pragma unroll
  for (int mi = 0; mi < 2; ++mi){
    int rb = row0 + wm*32 + mi*16 + lks*4;
    #pragma unroll
    for (int r = 0; r < 4; ++r){
      int rr = rb + r;
      if (rr < cnt){
        size_t orow = ((size_t)(base + rr) << 10) + nt*64;
        #pragma unroll
        for (int ni = 0; ni < 2; ++ni){
          int col = wn*32 + ni*16 + lr;
          float u0 = hh0[mi][ni][r];
          u0 = u0 > 0.f ? u0 : 0.f;
          hidh[orow + col] = f16bits((f16)(u0*hh1[mi][ni][r]));
        }
      }
    }
  }
}

// ---------------- layer-2 down-GEMM: fp16 hi-only ----------------
__global__ __launch_bounds__(256) void dnh_kernel(const u16* __restrict__ hidh,
    const u16* __restrict__ wdh,
    const int* __restrict__ offs, const int* __restrict__ counts, float* __restrict__ eo){
  int bx = blockIdx.x;
  int e  = bx >> 10;
  int mt = (bx >> 3) & 127;
  int nt = bx & 7;
  int base = offs[e], cnt = counts[e];
  int row0 = mt << 7;
  if (row0 >= cnt) return;
  __shared__ __align__(16) u16 Ah[2][4224];
  __shared__ __align__(16) u16 Bw[2][2176];
  int t = threadIdx.x, w = t >> 6, l = t & 63;
  int wm = w >> 1, wn = w & 1;
  int lr = l & 15, lks = l >> 4;
  int s0 = base + row0 + l;       s0 = s0 < NSLOT_ ? s0 : NSLOT_-1;
  int s1 = base + row0 + 64 + l;  s1 = s1 < NSLOT_ ? s1 : NSLOT_-1;
  const u16* sA0 = hidh + ((size_t)s0 << 10) + w*8;
  const u16* sA1 = hidh + ((size_t)s1 << 10) + w*8;
  size_t bcol = (size_t)(e*512 + nt*64);
  const u16* sB = wdh + ((bcol + l) << 10) + w*8;
  int dA0 = w*1056 + l*8, dA1 = w*1056 + 512 + l*8, dB = w*544 + l*8;
  f32x4 hh[4][2];
  #pragma unroll
  for (int i = 0; i < 4; ++i)
    #pragma unroll
    for (int j = 0; j < 2; ++j)
      #pragma unroll
      for (int r = 0; r < 4; ++r) hh[i][j][r] = 0.f;
#define STG_DH(buf, kc) do{ \
    gl_lds16(sA0 + (kc), &Ah[buf][dA0]); \
    gl_lds16(sA1 + (kc), &Ah[buf][dA1]); \
    gl_lds16(sB  + (kc), &Bw[buf][dB]); }while(0)
  STG_DH(0, 0);
  for (int ks = 0; ks < 32; ++ks){
    int cur = ks & 1, kc = ks*32;
    __syncthreads();
    if (ks < 31) STG_DH(cur^1, kc + 32);
    f16x8 ah[4], bh[2];
    #pragma unroll
    for (int mi = 0; mi < 4; ++mi) ah[mi] = *(const f16x8*)&Ah[cur][lks*1056 + (wm*64 + mi*16 + lr)*8];
    #pragma unroll
    for (int ni = 0; ni < 2; ++ni) bh[ni] = *(const f16x8*)&Bw[cur][lks*544 + (wn*32 + ni*16 + lr)*8];
    #pragma unroll
    for (int mi = 0; mi < 4; ++mi)
      #pragma unroll
      for (int ni = 0; ni < 2; ++ni)
        hh[mi][ni] = __builtin_amdgcn_mfma_f32_16x16x32_f16(ah[mi], bh[ni], hh[mi][ni], 0, 0, 0);
  }
#undef STG_DH
  #pragma unroll
  for (int mi = 0; mi < 4; ++mi){
    int rb = row0 + wm*64 + mi*16 + lks*4;
    #pragma unroll
    for (int r = 0; r < 4; ++r){
      int rr = rb + r;
      if (rr < cnt){
        float* orow = eo + (((size_t)(base + rr)) << 9) + nt*64;
        #pragma unroll
        for (int ni = 0; ni < 2; ++ni)
          orow[wn*32 + ni*16 + lr] = hh[mi][ni][r];
      }
    }
  }
}

// ---------------- gather + residual ----------------
__global__ __launch_bounds__(128) void gather_kernel(const float* __restrict__ xin,
    const float* __restrict__ eo, const int* __restrict__ slot_of, const float* __restrict__ wv,
    float* __restrict__ out){
  int n = blockIdx.x, t = threadIdx.x;
  int s0 = slot_of[2*n], s1 = slot_of[2*n+1];
  double w0 = wv[2*n], w1 = wv[2*n+1];
  float4 xi = *(const float4*)&xin[((size_t)n << 9) + t*4];
  float4 e0 = *(const float4*)&eo[((size_t)s0 << 9) + t*4];
  float4 e1 = *(const float4*)&eo[((size_t)s1 << 9) + t*4];
  float4 o;
  o.x = (float)((double)xi.x + w0*(double)e0.x + w1*(double)e1.x);
  o.y = (float)((double)xi.y + w0*(double)e0.y + w1*(double)e1.y);
  o.z = (float)((double)xi.z + w0*(double)e0.z + w1*(double)e1.z);
  o.w = (float)((double)xi.w + w0*(double)e0.w + w1*(double)e1.w);
  *(float4*)&out[((size_t)n << 9) + t*4] = o;
}

extern "C" void kernel_launch(void* const* d_in, const int* in_sizes, int n_in,
                              void* d_out, int out_size, void* d_ws, size_t ws_size,
                              hipStream_t stream) {
  (void)in_sizes; (void)n_in; (void)out_size; (void)ws_size;
  const float* x0   = (const float*)d_in[0];
  const int*   sid  = (const int*)  d_in[1];
  const float* ln_g = (const float*)d_in[2];
  const float* ln_b = (const float*)d_in[3];
  const float* semb = (const float*)d_in[4];
  const float* h1w  = (const float*)d_in[5];
  const float* h1b  = (const float*)d_in[6];
  const float* h2w  = (const float*)d_in[7];
  const float* h2b  = (const float*)d_in[8];
  const float* s1w  = (const float*)d_in[9];
  const float* s1b  = (const float*)d_in[10];
  const float* s2w  = (const float*)d_in[11];
  const float* s2b  = (const float*)d_in[12];
  const float* g1w  = (const float*)d_in[13];
  const float* g1b  = (const float*)d_in[14];
  const float* g2w  = (const float*)d_in[15];
  const float* g2b  = (const float*)d_in[16];
  const float* wi0  = (const float*)d_in[17];
  const float* wi1  = (const float*)d_in[18];
  const float* wo   = (const float*)d_in[19];

  char* W = (char*)d_ws;
  float*  h      = (float*)(W + 0);                  // 16 MB
  u16*    hfh    = (u16*)  (W + 16777216ULL);        // 8 MB
  u16*    hfl    = (u16*)  (W + 25165824ULL);        // 8 MB
  float*  eo32   = (float*)(W + 0);                  // 32 MB overlay of h+hfh+hfl (safe: h/hf consumed before eo written)
  u16*    hid16h = (u16*)  (W + 33554432ULL);        // 32 MB
  u16*    hid16l = (u16*)  (W + 67108864ULL);        // 32 MB
  u16*    w0Th   = (u16*)  (W + 100663296ULL);       // 8 MB each
  u16*    w0Tl   = (u16*)  (W + 109051904ULL);
  u16*    w1Th   = (u16*)  (W + 117440512ULL);
  u16*    w1Tl   = (u16*)  (W + 125829120ULL);
  u16*    woTh   = (u16*)  (W + 134217728ULL);
  u16*    woTl   = (u16*)  (W + 142606336ULL);
  u16*    g1Th   = (u16*)  (W + 150994944ULL);       // 256 KB
  u16*    g1Tl   = (u16*)  (W + 151257088ULL);       // 256 KB
  double* cs     = (double*)(W + 151519232ULL);
  double* cq     = (double*)(W + 151552000ULL);
  double* a64    = (double*)(W + 151584768ULL);
  double* c64    = (double*)(W + 151617536ULL);
  int*    idxa   = (int*)   (W + 151650304ULL);
  float*  warr   = (float*) (W + 151715840ULL);
  int*    tok_of = (int*)   (W + 151781376ULL);
  int*    slot_of= (int*)   (W + 151846912ULL);
  int*    counts = (int*)   (W + 151912448ULL);
  int*    cur    = counts + 8;
  int*    offs   = counts + 16;

  cvtT16<<<4096, 256, 0, stream>>>(wi0, w0Th, w0Tl, 512, 1024);
  cvtT16<<<4096, 256, 0, stream>>>(wi1, w1Th, w1Tl, 512, 1024);
  cvtT16<<<4096, 256, 0, stream>>>(wo,  woTh, woTl, 1024, 512);
  cvtT16<<<128,  256, 0, stream>>>(g1w, g1Th, g1Tl, 512, 256);

  for (int l = 0; l < 2; ++l){
    const float* xin = l ? (const float*)d_out : x0;
    ln_kernel<<<8192, 256, 0, stream>>>(xin, ln_g + l*512, ln_b + l*512, h);
    colstats<<<64, 256, 0, stream>>>(h, cs, cq);
    subj_kernel<<<8, 256, 0, stream>>>(sid, semb, h1w, h1b, h2w, h2b, s1w, s1b, s2w, s2b,
                                       cs, cq, a64, c64, l);
    hfcast<<<2048, 256, 0, stream>>>(h, a64, c64, hfh, hfl);
    zero_counts<<<1, 64, 0, stream>>>(counts);
    gate2_kernel<<<512, 256, 0, stream>>>(hfh, hfl, g1Th, g1Tl, g1b, g2w, g2b, idxa, warr, counts);
    offsets_kernel<<<1, 1, 0, stream>>>(counts, offs, cur);
    scatter_kernel<<<32, 256, 0, stream>>>(idxa, offs, cur, tok_of, slot_of);
    if (l == 0){
      up1_kernel<<<32768, 256, 0, stream>>>(hfh, hfl, w0Th, w0Tl, w1Th, w1Tl,
                                            tok_of, offs, counts, hid16h, hid16l);
      down1_kernel<<<8192, 256, 0, stream>>>(hid16h, hid16l, woTh, woTl, offs, counts, eo32);
    } else {
      uph_kernel<<<32768, 256, 0, stream>>>(hfh, w0Th, w1Th, tok_of, offs, counts, hid16h);
      dnh_kernel<<<8192, 256, 0, stream>>>(hid16h, woTh, offs, counts, eo32);
    }
    gather_kernel<<<8192, 128, 0, stream>>>(xin, eo32, slot_of, warr, (float*)d_out);
  }
}

// Round 5
// 868.715 us; speedup vs baseline: 3.5550x; 1.3485x over previous
//
#include <hip/hip_runtime.h>

typedef unsigned short u16;
typedef unsigned int   u32;
typedef _Float16       f16;
typedef __attribute__((ext_vector_type(8))) _Float16 f16x8;
typedef __attribute__((ext_vector_type(4))) float    f32x4;
typedef __attribute__((ext_vector_type(4))) double   dbl4;

#define NSLOT_ 16384   // N * K = 8192 * 2

__device__ __forceinline__ u16 f16bits(f16 h){ union{f16 f; u16 u;} x; x.f = h; return x.u; }

__device__ __forceinline__ void gl_lds16(const void* gptr, void* lptr){
  __builtin_amdgcn_global_load_lds((const __attribute__((address_space(1))) u32*)gptr,
                                   (__attribute__((address_space(3))) u32*)lptr, 16, 0, 0);
}

// swizzled LDS offset (u16 units) for row-pair-interleaved layout, BK=32.
// position(row, kc16') at (row>>1)*64 + kc16'*16 + (row&1)*8 ; kc16' = lks ^ ((row>>1)&3)
__device__ __forceinline__ int roff(int row, int lks){
  return ((row >> 1) << 6) + ((lks ^ ((row >> 1) & 3)) << 4) + ((row & 1) << 3);
}

// ---------------- per-token LayerNorm over D=512 (f64 math, f32 out) ----------------
__global__ __launch_bounds__(256) void ln_kernel(const float* __restrict__ x,
    const float* __restrict__ g, const float* __restrict__ bb, float* __restrict__ h){
  int n = blockIdx.x, t = threadIdx.x;
  const float* xr = x + ((size_t)n << 9);
  float2 v = *(const float2*)&xr[t*2];
  double vx = v.x, vy = v.y;
  double s = vx + vy;
  double q = vx*vx + vy*vy;
  #pragma unroll
  for (int o = 32; o > 0; o >>= 1){ s += __shfl_down(s, o, 64); q += __shfl_down(q, o, 64); }
  __shared__ double ls[4], lq_[4];
  __shared__ double sm, sv;
  int wid = t >> 6, lane = t & 63;
  if (lane == 0){ ls[wid] = s; lq_[wid] = q; }
  __syncthreads();
  if (t == 0){
    double S = ls[0]+ls[1]+ls[2]+ls[3], Q = lq_[0]+lq_[1]+lq_[2]+lq_[3];
    double mean = S * (1.0/512.0);
    double var  = Q * (1.0/512.0) - mean*mean;
    sm = mean; sv = 1.0/sqrt(var + 1e-5);
  }
  __syncthreads();
  double mean = sm, inv = sv;
  int d = t*2;
  float2 o;
  o.x = (float)((vx - mean)*inv*(double)g[d]   + (double)bb[d]);
  o.y = (float)((vy - mean)*inv*(double)g[d+1] + (double)bb[d+1]);
  *(float2*)&h[((size_t)n<<9) + d] = o;
}

// ---------------- column stats over T per (b,d), f64 accum from f32 h ----------------
__global__ __launch_bounds__(256) void colstats(const float* __restrict__ h,
    double* __restrict__ cs, double* __restrict__ cq){
  int bid = blockIdx.x;
  int b = bid >> 3, ch = bid & 7;
  int t = threadIdx.x;
  int col = ch*64 + (t & 63);
  int tp = t >> 6;
  const float* base = h + ((size_t)b << 19);
  double s = 0.0, q = 0.0;
  for (int tt = tp; tt < 1024; tt += 4){
    double v = (double)base[((size_t)tt << 9) + col];
    s += v; q += v*v;
  }
  __shared__ double ls[4][64], lq[4][64];
  ls[tp][t & 63] = s; lq[tp][t & 63] = q;
  __syncthreads();
  if (tp == 0){
    double S = ls[0][t]+ls[1][t]+ls[2][t]+ls[3][t];
    double Q = lq[0][t]+lq[1][t]+lq[2][t]+lq[3][t];
    cs[(b<<9)+col] = S; cq[(b<<9)+col] = Q;
  }
}

// ---------------- subject MLP -> per-(b,d) affine a,c (f64), one block per b ----------------
__global__ __launch_bounds__(256) void subj_kernel(const int* __restrict__ sid,
    const float* __restrict__ semb,
    const float* __restrict__ h1w, const float* __restrict__ h1b,
    const float* __restrict__ h2w, const float* __restrict__ h2b,
    const float* __restrict__ s1w, const float* __restrict__ s1b,
    const float* __restrict__ s2w, const float* __restrict__ s2b,
    const double* __restrict__ cs, const double* __restrict__ cq,
    double* __restrict__ a64, double* __restrict__ c64, int l){
  __shared__ double ev[64], hid1[128], hh[128], sh[64], sp[1024];
  int t = threadIdx.x;
  int b = blockIdx.x;
  int s = sid[b];
  if (t < 64) ev[t] = (double)semb[l*4096 + s*64 + t];
  __syncthreads();
  if (t < 128){
    double acc = (double)h1b[l*128 + t];
    for (int i = 0; i < 64; ++i) acc += ev[i]*(double)h1w[l*8192 + i*128 + t];
    hid1[t] = acc > 0.0 ? acc : 0.0;
  }
  __syncthreads();
  if (t < 128){
    double acc = (double)h2b[l*128 + t];
    for (int i = 0; i < 128; ++i) acc += hid1[i]*(double)h2w[l*16384 + i*128 + t];
    hh[t] = acc;
  }
  __syncthreads();
  if (t < 64){
    double acc = (double)s1b[l*64 + t];
    for (int i = 0; i < 128; ++i) acc += hh[i]*(double)s1w[l*8192 + i*64 + t];
    sh[t] = acc > 0.0 ? acc : 0.0;
  }
  __syncthreads();
  for (int m = t; m < 1024; m += 256){
    double acc = (double)s2b[l*1024 + m];
    for (int j = 0; j < 64; ++j) acc += sh[j]*(double)s2w[l*65536 + j*1024 + m];
    sp[m] = acc;
  }
  __syncthreads();
  for (int d = t; d < 512; d += 256){
    double mu  = cs[(b<<9)+d] * (1.0/1024.0);
    double var = cq[(b<<9)+d] * (1.0/1024.0) - mu*mu;
    double inv = 1.0/sqrt(var + 1e-8);
    double spv = sp[d];
    double gamma = (spv > 30.0 ? spv : log1p(exp(spv))) + 1e-8;
    double beta  = sp[512 + d];
    double A = gamma * inv;
    a64[(b<<9)+d] = A;
    c64[(b<<9)+d] = beta - mu*A;
  }
}

// ---------------- hf = h*a + c -> fp16 hi/lo' (lo scaled 2^11) ----------------
__global__ __launch_bounds__(256) void hfcast(const float* __restrict__ h,
    const double* __restrict__ a64, const double* __restrict__ c64,
    u16* __restrict__ hfh, u16* __restrict__ hfl){
  size_t i0 = ((size_t)blockIdx.x*256 + threadIdx.x) * 8;
  int n = (int)(i0 >> 9);
  int d0 = (int)(i0 & 511);
  int b = n >> 10;
  float4 x0 = *(const float4*)&h[i0];
  float4 x1 = *(const float4*)&h[i0 + 4];
  dbl4 a0 = *(const dbl4*)&a64[(b<<9) + d0];
  dbl4 a1 = *(const dbl4*)&a64[(b<<9) + d0 + 4];
  dbl4 c0 = *(const dbl4*)&c64[(b<<9) + d0];
  dbl4 c1 = *(const dbl4*)&c64[(b<<9) + d0 + 4];
  float f[8];
  f[0] = (float)((double)x0.x*a0[0] + c0[0]);
  f[1] = (float)((double)x0.y*a0[1] + c0[1]);
  f[2] = (float)((double)x0.z*a0[2] + c0[2]);
  f[3] = (float)((double)x0.w*a0[3] + c0[3]);
  f[4] = (float)((double)x1.x*a1[0] + c1[0]);
  f[5] = (float)((double)x1.y*a1[1] + c1[1]);
  f[6] = (float)((double)x1.z*a1[2] + c1[2]);
  f[7] = (float)((double)x1.w*a1[3] + c1[3]);
  ushort4 oh0, oh1, ol0, ol1;
  u16 vh[8], vl[8];
  #pragma unroll
  for (int j = 0; j < 8; ++j){
    f16 hi = (f16)f[j];
    float rem = (f[j] - (float)hi) * 2048.f;
    f16 lo = (f16)rem;
    vh[j] = f16bits(hi); vl[j] = f16bits(lo);
  }
  oh0.x=vh[0]; oh0.y=vh[1]; oh0.z=vh[2]; oh0.w=vh[3];
  oh1.x=vh[4]; oh1.y=vh[5]; oh1.z=vh[6]; oh1.w=vh[7];
  ol0.x=vl[0]; ol0.y=vl[1]; ol0.z=vl[2]; ol0.w=vl[3];
  ol1.x=vl[4]; ol1.y=vl[5]; ol1.z=vl[6]; ol1.w=vl[7];
  *(ushort4*)&hfh[i0]   = oh0;
  *(ushort4*)&hfh[i0+4] = oh1;
  *(ushort4*)&hfl[i0]   = ol0;
  *(ushort4*)&hfl[i0+4] = ol1;
}

__global__ void zero_counts(int* __restrict__ counts){
  if (threadIdx.x < 8) counts[threadIdx.x] = 0;
}

// ---------------- gating: fp16-split MFMA (f32 accum) + f64 finish, top-2 ----------------
__global__ __launch_bounds__(256) void gate2_kernel(const u16* __restrict__ hfh,
    const u16* __restrict__ hfl, const u16* __restrict__ g1Th, const u16* __restrict__ g1Tl,
    const float* __restrict__ g1b, const float* __restrict__ g2w, const float* __restrict__ g2b,
    int* __restrict__ idxo, float* __restrict__ wo_, int* __restrict__ counts){
  __shared__ double hid_s[16][258];
  __shared__ double lg[16*8];
  __shared__ int lcnt[8];
  int t = threadIdx.x, w = t >> 6, l = t & 63;
  int tok0 = blockIdx.x << 4;
  if (t < 8) lcnt[t] = 0;
  int lr = l & 15, lks = l >> 4;
  const u16* ahp = hfh + ((size_t)(tok0 + lr) << 9) + lks*8;
  const u16* alp = hfl + ((size_t)(tok0 + lr) << 9) + lks*8;
  const u16* bhp[4]; const u16* blp[4];
  #pragma unroll
  for (int nf = 0; nf < 4; ++nf){
    int col = w*64 + nf*16 + lr;
    bhp[nf] = g1Th + ((size_t)col << 9) + lks*8;
    blp[nf] = g1Tl + ((size_t)col << 9) + lks*8;
  }
  f32x4 hh[4], cr[4];
  #pragma unroll
  for (int nf = 0; nf < 4; ++nf)
    #pragma unroll
    for (int r = 0; r < 4; ++r){ hh[nf][r] = 0.f; cr[nf][r] = 0.f; }
  f16x8 ah = *(const f16x8*)ahp;
  f16x8 al = *(const f16x8*)alp;
  for (int kc = 0; kc < 512; kc += 32){
    int kn = (kc + 32) & 511;                 // wraps; last prefetch discarded
    f16x8 ahn = *(const f16x8*)(ahp + kn);
    f16x8 aln = *(const f16x8*)(alp + kn);
    #pragma unroll
    for (int nf = 0; nf < 4; ++nf){
      f16x8 bh = *(const f16x8*)(bhp[nf] + kc);
      f16x8 bl = *(const f16x8*)(blp[nf] + kc);
      hh[nf] = __builtin_amdgcn_mfma_f32_16x16x32_f16(ah, bh, hh[nf], 0, 0, 0);
      cr[nf] = __builtin_amdgcn_mfma_f32_16x16x32_f16(ah, bl, cr[nf], 0, 0, 0);
      cr[nf] = __builtin_amdgcn_mfma_f32_16x16x32_f16(al, bh, cr[nf], 0, 0, 0);
    }
    ah = ahn; al = aln;
  }
  #pragma unroll
  for (int nf = 0; nf < 4; ++nf){
    int col = w*64 + nf*16 + lr;
    double gb = (double)g1b[col];
    #pragma unroll
    for (int r = 0; r < 4; ++r){
      int row = lks*4 + r;
      double v = (double)hh[nf][r] + (double)cr[nf][r]*(1.0/2048.0) + gb;
      hid_s[row][col] = v > 0.0 ? v : 0.0;
    }
  }
  __syncthreads();
  if (t < 128){
    int tok = t >> 3, e = t & 7;
    double la = (double)g2b[e];
    for (int k = 0; k < 256; ++k) la += hid_s[tok][k]*(double)g2w[(k<<3)+e];
    lg[(tok<<3)+e] = la;
  }
  __syncthreads();
  if (t < 16){
    double l0[8];
    #pragma unroll
    for (int e = 0; e < 8; ++e) l0[e] = lg[(t<<3)+e];
    double m = l0[0];
    #pragma unroll
    for (int e = 1; e < 8; ++e) m = fmax(m, l0[e]);
    double p[8]; double s = 0.0;
    #pragma unroll
    for (int e = 0; e < 8; ++e){ p[e] = exp(l0[e]-m); s += p[e]; }
    double b1 = -1e300, b2 = -1e300; int i1 = 0, i2 = 1;
    #pragma unroll
    for (int e = 0; e < 8; ++e){
      double v = l0[e];
      if (v > b1){ b2 = b1; i2 = i1; b1 = v; i1 = e; }
      else if (v > b2){ b2 = v; i2 = e; }
    }
    double pr1 = p[i1]/s, pr2 = p[i2]/s;
    double den = pr1 + pr2 + 1e-8;
    int n = tok0 + t;
    idxo[2*n] = i1; idxo[2*n+1] = i2;
    wo_[2*n] = (float)(pr1/den); wo_[2*n+1] = (float)(pr2/den);
    atomicAdd(&lcnt[i1], 1); atomicAdd(&lcnt[i2], 1);
  }
  __syncthreads();
  if (t < 8) atomicAdd(&counts[t], lcnt[t]);
}

__global__ void offsets_kernel(const int* __restrict__ counts, int* __restrict__ offs,
                               int* __restrict__ cur){
  if (threadIdx.x == 0 && blockIdx.x == 0){
    int run = 0;
    for (int e = 0; e < 8; ++e){ offs[e] = run; run += counts[e]; cur[e] = 0; }
  }
}

__global__ __launch_bounds__(256) void scatter_kernel(const int* __restrict__ idx,
    const int* __restrict__ offs, int* __restrict__ cur,
    int* __restrict__ tok_of, int* __restrict__ slot_of){
  __shared__ int lcnt[8], lbase[8];
  int t = threadIdx.x;
  int n = blockIdx.x*256 + t;
  if (t < 8) lcnt[t] = 0;
  __syncthreads();
  int e0 = idx[2*n], e1 = idx[2*n+1];
  int p0 = atomicAdd(&lcnt[e0], 1);
  int p1 = atomicAdd(&lcnt[e1], 1);
  __syncthreads();
  if (t < 8) lbase[t] = atomicAdd(&cur[t], lcnt[t]);
  __syncthreads();
  int s0 = offs[e0] + lbase[e0] + p0;
  int s1 = offs[e1] + lbase[e1] + p1;
  tok_of[s0] = n; tok_of[s1] = n;
  slot_of[2*n] = s0; slot_of[2*n+1] = s1;
}

// ---------------- weight transpose + fp16 hi/lo' split: [E][R][C] -> [E][C][R] ----------------
__global__ __launch_bounds__(256) void cvtT16(const float* __restrict__ src,
    u16* __restrict__ dh, u16* __restrict__ dl, int R, int C){
  int bx = blockIdx.x;
  int tilesC = C >> 5, tilesR = R >> 5;
  int e = bx / (tilesR*tilesC);
  int rem = bx % (tilesR*tilesC);
  int rt = rem / tilesC, ct = rem % tilesC;
  __shared__ float tile[32][33];
  int t = threadIdx.x;
  int j = t & 31, i0 = t >> 5;
  const float* s = src + (size_t)e*R*C + (size_t)(rt*32)*C + ct*32;
  for (int ii = i0; ii < 32; ii += 8) tile[ii][j] = s[(size_t)ii*C + j];
  __syncthreads();
  size_t ob = (size_t)e*R*C + (size_t)(ct*32)*R + rt*32;
  for (int ii = i0; ii < 32; ii += 8){
    float v = tile[j][ii];
    f16 hi = (f16)v;
    float rem2 = (v - (float)hi) * 2048.f;
    f16 lo = (f16)rem2;
    dh[ob + (size_t)ii*R + j] = f16bits(hi);
    dl[ob + (size_t)ii*R + j] = f16bits(lo);
  }
}

// ---------------- layer-1 up-GEMM: fp16-split, 128r x 64c, all-LDS swizzled ----------------
// grid: e(8) x mt(128; 128 rows) x nt(16; 64 cols)
__global__ __launch_bounds__(256) void up1_kernel(const u16* __restrict__ hfh,
    const u16* __restrict__ hfl,
    const u16* __restrict__ w0h, const u16* __restrict__ w0l,
    const u16* __restrict__ w1h, const u16* __restrict__ w1l,
    const int* __restrict__ tok_of, const int* __restrict__ offs, const int* __restrict__ counts,
    u16* __restrict__ hidh, u16* __restrict__ hidl){
  int bx = blockIdx.x;
  int e  = bx >> 11;
  int mt = (bx >> 4) & 127;
  int nt = bx & 15;
  int base = offs[e], cnt = counts[e];
  int row0 = mt << 7;
  if (row0 >= cnt) return;
  __shared__ __align__(16) u16 Ah[2][4096], Alo[2][4096];
  __shared__ __align__(16) u16 B0h[2][2048], B0l[2][2048], B1h[2][2048], B1l[2][2048];
  int t = threadIdx.x, w = t >> 6, l = t & 63;
  int wm = w >> 1, wn = w & 1;
  int lr = l & 15, lks = l >> 4;
  // staging source setup (row-pair-interleave + XOR pre-swizzle)
  int riw = ((l >> 3) << 1) | (l & 1);
  int kc16s = ((((l >> 1) & 3) ^ ((l >> 3) & 3)) << 3);
  int ar1 = w*16 + riw;
  int tokA1, tokA2;
  { int ss = base + row0 + ar1;      ss = ss < NSLOT_ ? ss : NSLOT_-1; tokA1 = tok_of[ss]; }
  { int ss = base + row0 + 64 + ar1; ss = ss < NSLOT_ ? ss : NSLOT_-1; tokA2 = tok_of[ss]; }
  const u16* sAh1 = hfh + ((size_t)tokA1 << 9) + kc16s;
  const u16* sAh2 = hfh + ((size_t)tokA2 << 9) + kc16s;
  const u16* sAl1 = hfl + ((size_t)tokA1 << 9) + kc16s;
  const u16* sAl2 = hfl + ((size_t)tokA2 << 9) + kc16s;
  size_t bcol = (size_t)(e*1024 + nt*64);
  size_t bci = (bcol + (size_t)ar1) << 9;
  const u16* sB0h = w0h + bci + kc16s;
  const u16* sB0l = w0l + bci + kc16s;
  const u16* sB1h = w1h + bci + kc16s;
  const u16* sB1l = w1l + bci + kc16s;
  // fragment LDS offsets (constant per thread)
  int aoff[4], boff[2];
  #pragma unroll
  for (int mi = 0; mi < 4; ++mi) aoff[mi] = roff(wm*64 + mi*16 + lr, lks);
  #pragma unroll
  for (int ni = 0; ni < 2; ++ni) boff[ni] = roff(wn*32 + ni*16 + lr, lks);
  f32x4 hh0[4][2], cr0[4][2], hh1[4][2], cr1[4][2];
  #pragma unroll
  for (int i = 0; i < 4; ++i)
    #pragma unroll
    for (int j = 0; j < 2; ++j)
      #pragma unroll
      for (int r = 0; r < 4; ++r){ hh0[i][j][r]=0.f; cr0[i][j][r]=0.f; hh1[i][j][r]=0.f; cr1[i][j][r]=0.f; }
#define STG_U(buf, kc) do{ \
    gl_lds16(sAh1 + (kc), &Ah[buf][t*8]); \
    gl_lds16(sAh2 + (kc), &Ah[buf][2048 + t*8]); \
    gl_lds16(sAl1 + (kc), &Alo[buf][t*8]); \
    gl_lds16(sAl2 + (kc), &Alo[buf][2048 + t*8]); \
    gl_lds16(sB0h + (kc), &B0h[buf][t*8]); \
    gl_lds16(sB0l + (kc), &B0l[buf][t*8]); \
    gl_lds16(sB1h + (kc), &B1h[buf][t*8]); \
    gl_lds16(sB1l + (kc), &B1l[buf][t*8]); }while(0)
  STG_U(0, 0);
  for (int ks = 0; ks < 16; ++ks){
    int cur = ks & 1;
    __syncthreads();
    if (ks < 15) STG_U(cur^1, (ks+1)*32);
    f16x8 ah[4], al[4], b0hv[2], b0lv[2], b1hv[2], b1lv[2];
    #pragma unroll
    for (int mi = 0; mi < 4; ++mi){
      ah[mi] = *(const f16x8*)&Ah[cur][aoff[mi]];
      al[mi] = *(const f16x8*)&Alo[cur][aoff[mi]];
    }
    #pragma unroll
    for (int ni = 0; ni < 2; ++ni){
      b0hv[ni] = *(const f16x8*)&B0h[cur][boff[ni]];
      b0lv[ni] = *(const f16x8*)&B0l[cur][boff[ni]];
      b1hv[ni] = *(const f16x8*)&B1h[cur][boff[ni]];
      b1lv[ni] = *(const f16x8*)&B1l[cur][boff[ni]];
    }
    #pragma unroll
    for (int mi = 0; mi < 4; ++mi)
      #pragma unroll
      for (int ni = 0; ni < 2; ++ni){
        hh0[mi][ni] = __builtin_amdgcn_mfma_f32_16x16x32_f16(ah[mi], b0hv[ni], hh0[mi][ni], 0, 0, 0);
        hh1[mi][ni] = __builtin_amdgcn_mfma_f32_16x16x32_f16(ah[mi], b1hv[ni], hh1[mi][ni], 0, 0, 0);
        cr0[mi][ni] = __builtin_amdgcn_mfma_f32_16x16x32_f16(ah[mi], b0lv[ni], cr0[mi][ni], 0, 0, 0);
        cr0[mi][ni] = __builtin_amdgcn_mfma_f32_16x16x32_f16(al[mi], b0hv[ni], cr0[mi][ni], 0, 0, 0);
        cr1[mi][ni] = __builtin_amdgcn_mfma_f32_16x16x32_f16(ah[mi], b1lv[ni], cr1[mi][ni], 0, 0, 0);
        cr1[mi][ni] = __builtin_amdgcn_mfma_f32_16x16x32_f16(al[mi], b1hv[ni], cr1[mi][ni], 0, 0, 0);
      }
  }
#undef STG_U
  #pragma unroll
  for (int mi = 0; mi < 4; ++mi){
    int rb = row0 + wm*64 + mi*16 + lks*4;
    #pragma unroll
    for (int r = 0; r < 4; ++r){
      int rr = rb + r;
      if (rr < cnt){
        size_t orow = ((size_t)(base + rr) << 10) + nt*64;
        #pragma unroll
        for (int ni = 0; ni < 2; ++ni){
          int col = wn*32 + ni*16 + lr;
          float u0 = hh0[mi][ni][r] + cr0[mi][ni][r]*(1.f/2048.f);
          float u1 = hh1[mi][ni][r] + cr1[mi][ni][r]*(1.f/2048.f);
          u0 = u0 > 0.f ? u0 : 0.f;
          float v = u0*u1;
          f16 vh = (f16)v;
          float rem = (v - (float)vh)*2048.f;
          hidh[orow + col] = f16bits(vh);
          hidl[orow + col] = f16bits((f16)rem);
        }
      }
    }
  }
}

// ---------------- layer-1 down-GEMM: fp16-split, 128r x 64c, all-LDS swizzled ----------------
// grid: e(8) x mt(128) x nt(8)
__global__ __launch_bounds__(256) void down1_kernel(const u16* __restrict__ hidh,
    const u16* __restrict__ hidl, const u16* __restrict__ wdh, const u16* __restrict__ wdl,
    const int* __restrict__ offs, const int* __restrict__ counts, float* __restrict__ eo){
  int bx = blockIdx.x;
  int e  = bx >> 10;
  int mt = (bx >> 3) & 127;
  int nt = bx & 7;
  int base = offs[e], cnt = counts[e];
  int row0 = mt << 7;
  if (row0 >= cnt) return;
  __shared__ __align__(16) u16 Ah[2][4096], Alo[2][4096];
  __shared__ __align__(16) u16 Bh[2][2048], Bl[2][2048];
  int t = threadIdx.x, w = t >> 6, l = t & 63;
  int wm = w >> 1, wn = w & 1;
  int lr = l & 15, lks = l >> 4;
  int riw = ((l >> 3) << 1) | (l & 1);
  int kc16s = ((((l >> 1) & 3) ^ ((l >> 3) & 3)) << 3);
  int ar1 = w*16 + riw;
  int sA1c = base + row0 + ar1;      sA1c = sA1c < NSLOT_ ? sA1c : NSLOT_-1;
  int sA2c = base + row0 + 64 + ar1; sA2c = sA2c < NSLOT_ ? sA2c : NSLOT_-1;
  const u16* sAh1 = hidh + ((size_t)sA1c << 10) + kc16s;
  const u16* sAh2 = hidh + ((size_t)sA2c << 10) + kc16s;
  const u16* sAl1 = hidl + ((size_t)sA1c << 10) + kc16s;
  const u16* sAl2 = hidl + ((size_t)sA2c << 10) + kc16s;
  size_t bcol = (size_t)(e*512 + nt*64);
  size_t bci = (bcol + (size_t)ar1) << 10;
  const u16* sBh = wdh + bci + kc16s;
  const u16* sBl = wdl + bci + kc16s;
  int aoff[4], boff[2];
  #pragma unroll
  for (int mi = 0; mi < 4; ++mi) aoff[mi] = roff(wm*64 + mi*16 + lr, lks);
  #pragma unroll
  for (int ni = 0; ni < 2; ++ni) boff[ni] = roff(wn*32 + ni*16 + lr, lks);
  f32x4 hh[4][2], cr[4][2];
  #pragma unroll
  for (int i = 0; i < 4; ++i)
    #pragma unroll
    for (int j = 0; j < 2; ++j)
      #pragma unroll
      for (int r = 0; r < 4; ++r){ hh[i][j][r]=0.f; cr[i][j][r]=0.f; }
#define STG_D(buf, kc) do{ \
    gl_lds16(sAh1 + (kc), &Ah[buf][t*8]); \
    gl_lds16(sAh2 + (kc), &Ah[buf][2048 + t*8]); \
    gl_lds16(sAl1 + (kc), &Alo[buf][t*8]); \
    gl_lds16(sAl2 + (kc), &Alo[buf][2048 + t*8]); \
    gl_lds16(sBh + (kc), &Bh[buf][t*8]); \
    gl_lds16(sBl + (kc), &Bl[buf][t*8]); }while(0)
  STG_D(0, 0);
  for (int ks = 0; ks < 32; ++ks){
    int cur = ks & 1;
    __syncthreads();
    if (ks < 31) STG_D(cur^1, (ks+1)*32);
    f16x8 ah[4], al[4], bh[2], bl[2];
    #pragma unroll
    for (int mi = 0; mi < 4; ++mi){
      ah[mi] = *(const f16x8*)&Ah[cur][aoff[mi]];
      al[mi] = *(const f16x8*)&Alo[cur][aoff[mi]];
    }
    #pragma unroll
    for (int ni = 0; ni < 2; ++ni){
      bh[ni] = *(const f16x8*)&Bh[cur][boff[ni]];
      bl[ni] = *(const f16x8*)&Bl[cur][boff[ni]];
    }
    #pragma unroll
    for (int mi = 0; mi < 4; ++mi)
      #pragma unroll
      for (int ni = 0; ni < 2; ++ni){
        hh[mi][ni] = __builtin_amdgcn_mfma_f32_16x16x32_f16(ah[mi], bh[ni], hh[mi][ni], 0, 0, 0);
        cr[mi][ni] = __builtin_amdgcn_mfma_f32_16x16x32_f16(ah[mi], bl[ni], cr[mi][ni], 0, 0, 0);
        cr[mi][ni] = __builtin_amdgcn_mfma_f32_16x16x32_f16(al[mi], bh[ni], cr[mi][ni], 0, 0, 0);
      }
  }
#undef STG_D
  #pragma unroll
  for (int mi = 0; mi < 4; ++mi){
    int rb = row0 + wm*64 + mi*16 + lks*4;
    #pragma unroll
    for (int r = 0; r < 4; ++r){
      int rr = rb + r;
      if (rr < cnt){
        float* orow = eo + (((size_t)(base + rr)) << 9) + nt*64;
        #pragma unroll
        for (int ni = 0; ni < 2; ++ni)
          orow[wn*32 + ni*16 + lr] = hh[mi][ni][r] + cr[mi][ni][r]*(1.f/2048.f);
      }
    }
  }
}

// ---------------- layer-2 up-GEMM: fp16 hi-only, 128r x 64c ----------------
__global__ __launch_bounds__(256) void uph_kernel(const u16* __restrict__ hfh,
    const u16* __restrict__ w0h, const u16* __restrict__ w1h,
    const int* __restrict__ tok_of, const int* __restrict__ offs, const int* __restrict__ counts,
    u16* __restrict__ hidh){
  int bx = blockIdx.x;
  int e  = bx >> 11;
  int mt = (bx >> 4) & 127;
  int nt = bx & 15;
  int base = offs[e], cnt = counts[e];
  int row0 = mt << 7;
  if (row0 >= cnt) return;
  __shared__ __align__(16) u16 Ah[2][4096];
  __shared__ __align__(16) u16 B0h[2][2048], B1h[2][2048];
  int t = threadIdx.x, w = t >> 6, l = t & 63;
  int wm = w >> 1, wn = w & 1;
  int lr = l & 15, lks = l >> 4;
  int riw = ((l >> 3) << 1) | (l & 1);
  int kc16s = ((((l >> 1) & 3) ^ ((l >> 3) & 3)) << 3);
  int ar1 = w*16 + riw;
  int tokA1, tokA2;
  { int ss = base + row0 + ar1;      ss = ss < NSLOT_ ? ss : NSLOT_-1; tokA1 = tok_of[ss]; }
  { int ss = base + row0 + 64 + ar1; ss = ss < NSLOT_ ? ss : NSLOT_-1; tokA2 = tok_of[ss]; }
  const u16* sAh1 = hfh + ((size_t)tokA1 << 9) + kc16s;
  const u16* sAh2 = hfh + ((size_t)tokA2 << 9) + kc16s;
  size_t bcol = (size_t)(e*1024 + nt*64);
  size_t bci = (bcol + (size_t)ar1) << 9;
  const u16* sB0 = w0h + bci + kc16s;
  const u16* sB1 = w1h + bci + kc16s;
  int aoff[4], boff[2];
  #pragma unroll
  for (int mi = 0; mi < 4; ++mi) aoff[mi] = roff(wm*64 + mi*16 + lr, lks);
  #pragma unroll
  for (int ni = 0; ni < 2; ++ni) boff[ni] = roff(wn*32 + ni*16 + lr, lks);
  f32x4 hh0[4][2], hh1[4][2];
  #pragma unroll
  for (int i = 0; i < 4; ++i)
    #pragma unroll
    for (int j = 0; j < 2; ++j)
      #pragma unroll
      for (int r = 0; r < 4; ++r){ hh0[i][j][r]=0.f; hh1[i][j][r]=0.f; }
#define STG_UH(buf, kc) do{ \
    gl_lds16(sAh1 + (kc), &Ah[buf][t*8]); \
    gl_lds16(sAh2 + (kc), &Ah[buf][2048 + t*8]); \
    gl_lds16(sB0 + (kc), &B0h[buf][t*8]); \
    gl_lds16(sB1 + (kc), &B1h[buf][t*8]); }while(0)
  STG_UH(0, 0);
  for (int ks = 0; ks < 16; ++ks){
    int cur = ks & 1;
    __syncthreads();
    if (ks < 15) STG_UH(cur^1, (ks+1)*32);
    f16x8 ah[4], b0v[2], b1v[2];
    #pragma unroll
    for (int mi = 0; mi < 4; ++mi) ah[mi] = *(const f16x8*)&Ah[cur][aoff[mi]];
    #pragma unroll
    for (int ni = 0; ni < 2; ++ni){
      b0v[ni] = *(const f16x8*)&B0h[cur][boff[ni]];
      b1v[ni] = *(const f16x8*)&B1h[cur][boff[ni]];
    }
    #pragma unroll
    for (int mi = 0; mi < 4; ++mi)
      #pragma unroll
      for (int ni = 0; ni < 2; ++ni){
        hh0[mi][ni] = __builtin_amdgcn_mfma_f32_16x16x32_f16(ah[mi], b0v[ni], hh0[mi][ni], 0, 0, 0);
        hh1[mi][ni] = __builtin_amdgcn_mfma_f32_16x16x32_f16(ah[mi], b1v[ni], hh1[mi][ni], 0, 0, 0);
      }
  }
#undef STG_UH
  #pragma unroll
  for (int mi = 0; mi < 4; ++mi){
    int rb = row0 + wm*64 + mi*16 + lks*4;
    #pragma unroll
    for (int r = 0; r < 4; ++r){
      int rr = rb + r;
      if (rr < cnt){
        size_t orow = ((size_t)(base + rr) << 10) + nt*64;
        #pragma unroll
        for (int ni = 0; ni < 2; ++ni){
          int col = wn*32 + ni*16 + lr;
          float u0 = hh0[mi][ni][r];
          u0 = u0 > 0.f ? u0 : 0.f;
          hidh[orow + col] = f16bits((f16)(u0*hh1[mi][ni][r]));
        }
      }
    }
  }
}

// ---------------- layer-2 down-GEMM: fp16 hi-only, 128r x 64c ----------------
__global__ __launch_bounds__(256) void dnh_kernel(const u16* __restrict__ hidh,
    const u16* __restrict__ wdh,
    const int* __restrict__ offs, const int* __restrict__ counts, float* __restrict__ eo){
  int bx = blockIdx.x;
  int e  = bx >> 10;
  int mt = (bx >> 3) & 127;
  int nt = bx & 7;
  int base = offs[e], cnt = counts[e];
  int row0 = mt << 7;
  if (row0 >= cnt) return;
  __shared__ __align__(16) u16 Ah[2][4096];
  __shared__ __align__(16) u16 Bh[2][2048];
  int t = threadIdx.x, w = t >> 6, l = t & 63;
  int wm = w >> 1, wn = w & 1;
  int lr = l & 15, lks = l >> 4;
  int riw = ((l >> 3) << 1) | (l & 1);
  int kc16s = ((((l >> 1) & 3) ^ ((l >> 3) & 3)) << 3);
  int ar1 = w*16 + riw;
  int sA1c = base + row0 + ar1;      sA1c = sA1c < NSLOT_ ? sA1c : NSLOT_-1;
  int sA2c = base + row0 + 64 + ar1; sA2c = sA2c < NSLOT_ ? sA2c : NSLOT_-1;
  const u16* sAh1 = hidh + ((size_t)sA1c << 10) + kc16s;
  const u16* sAh2 = hidh + ((size_t)sA2c << 10) + kc16s;
  size_t bcol = (size_t)(e*512 + nt*64);
  const u16* sB = wdh + ((bcol + (size_t)ar1) << 10) + kc16s;
  int aoff[4], boff[2];
  #pragma unroll
  for (int mi = 0; mi < 4; ++mi) aoff[mi] = roff(wm*64 + mi*16 + lr, lks);
  #pragma unroll
  for (int ni = 0; ni < 2; ++ni) boff[ni] = roff(wn*32 + ni*16 + lr, lks);
  f32x4 hh[4][2];
  #pragma unroll
  for (int i = 0; i < 4; ++i)
    #pragma unroll
    for (int j = 0; j < 2; ++j)
      #pragma unroll
      for (int r = 0; r < 4; ++r) hh[i][j][r] = 0.f;
#define STG_DH(buf, kc) do{ \
    gl_lds16(sAh1 + (kc), &Ah[buf][t*8]); \
    gl_lds16(sAh2 + (kc), &Ah[buf][2048 + t*8]); \
    gl_lds16(sB + (kc), &Bh[buf][t*8]); }while(0)
  STG_DH(0, 0);
  for (int ks = 0; ks < 32; ++ks){
    int cur = ks & 1;
    __syncthreads();
    if (ks < 31) STG_DH(cur^1, (ks+1)*32);
    f16x8 ah[4], bh[2];
    #pragma unroll
    for (int mi = 0; mi < 4; ++mi) ah[mi] = *(const f16x8*)&Ah[cur][aoff[mi]];
    #pragma unroll
    for (int ni = 0; ni < 2; ++ni) bh[ni] = *(const f16x8*)&Bh[cur][boff[ni]];
    #pragma unroll
    for (int mi = 0; mi < 4; ++mi)
      #pragma unroll
      for (int ni = 0; ni < 2; ++ni)
        hh[mi][ni] = __builtin_amdgcn_mfma_f32_16x16x32_f16(ah[mi], bh[ni], hh[mi][ni], 0, 0, 0);
  }
#undef STG_DH
  #pragma unroll
  for (int mi = 0; mi < 4; ++mi){
    int rb = row0 + wm*64 + mi*16 + lks*4;
    #pragma unroll
    for (int r = 0; r < 4; ++r){
      int rr = rb + r;
      if (rr < cnt){
        float* orow = eo + (((size_t)(base + rr)) << 9) + nt*64;
        #pragma unroll
        for (int ni = 0; ni < 2; ++ni)
          orow[wn*32 + ni*16 + lr] = hh[mi][ni][r];
      }
    }
  }
}

// ---------------- gather + residual ----------------
__global__ __launch_bounds__(128) void gather_kernel(const float* __restrict__ xin,
    const float* __restrict__ eo, const int* __restrict__ slot_of, const float* __restrict__ wv,
    float* __restrict__ out){
  int n = blockIdx.x, t = threadIdx.x;
  int s0 = slot_of[2*n], s1 = slot_of[2*n+1];
  double w0 = wv[2*n], w1 = wv[2*n+1];
  float4 xi = *(const float4*)&xin[((size_t)n << 9) + t*4];
  float4 e0 = *(const float4*)&eo[((size_t)s0 << 9) + t*4];
  float4 e1 = *(const float4*)&eo[((size_t)s1 << 9) + t*4];
  float4 o;
  o.x = (float)((double)xi.x + w0*(double)e0.x + w1*(double)e1.x);
  o.y = (float)((double)xi.y + w0*(double)e0.y + w1*(double)e1.y);
  o.z = (float)((double)xi.z + w0*(double)e0.z + w1*(double)e1.z);
  o.w = (float)((double)xi.w + w0*(double)e0.w + w1*(double)e1.w);
  *(float4*)&out[((size_t)n << 9) + t*4] = o;
}

extern "C" void kernel_launch(void* const* d_in, const int* in_sizes, int n_in,
                              void* d_out, int out_size, void* d_ws, size_t ws_size,
                              hipStream_t stream) {
  (void)in_sizes; (void)n_in; (void)out_size; (void)ws_size;
  const float* x0   = (const float*)d_in[0];
  const int*   sid  = (const int*)  d_in[1];
  const float* ln_g = (const float*)d_in[2];
  const float* ln_b = (const float*)d_in[3];
  const float* semb = (const float*)d_in[4];
  const float* h1w  = (const float*)d_in[5];
  const float* h1b  = (const float*)d_in[6];
  const float* h2w  = (const float*)d_in[7];
  const float* h2b  = (const float*)d_in[8];
  const float* s1w  = (const float*)d_in[9];
  const float* s1b  = (const float*)d_in[10];
  const float* s2w  = (const float*)d_in[11];
  const float* s2b  = (const float*)d_in[12];
  const float* g1w  = (const float*)d_in[13];
  const float* g1b  = (const float*)d_in[14];
  const float* g2w  = (const float*)d_in[15];
  const float* g2b  = (const float*)d_in[16];
  const float* wi0  = (const float*)d_in[17];
  const float* wi1  = (const float*)d_in[18];
  const float* wo   = (const float*)d_in[19];

  char* W = (char*)d_ws;
  float*  h      = (float*)(W + 0);                  // 16 MB
  u16*    hfh    = (u16*)  (W + 16777216ULL);        // 8 MB
  u16*    hfl    = (u16*)  (W + 25165824ULL);        // 8 MB
  float*  eo32   = (float*)(W + 0);                  // 32 MB overlay (h+hfh+hfl consumed first)
  u16*    hid16h = (u16*)  (W + 33554432ULL);        // 32 MB
  u16*    hid16l = (u16*)  (W + 67108864ULL);        // 32 MB
  u16*    w0Th   = (u16*)  (W + 100663296ULL);       // 8 MB each
  u16*    w0Tl   = (u16*)  (W + 109051904ULL);
  u16*    w1Th   = (u16*)  (W + 117440512ULL);
  u16*    w1Tl   = (u16*)  (W + 125829120ULL);
  u16*    woTh   = (u16*)  (W + 134217728ULL);
  u16*    woTl   = (u16*)  (W + 142606336ULL);
  u16*    g1Th   = (u16*)  (W + 150994944ULL);
  u16*    g1Tl   = (u16*)  (W + 151257088ULL);
  double* cs     = (double*)(W + 151519232ULL);
  double* cq     = (double*)(W + 151552000ULL);
  double* a64    = (double*)(W + 151584768ULL);
  double* c64    = (double*)(W + 151617536ULL);
  int*    idxa   = (int*)   (W + 151650304ULL);
  float*  warr   = (float*) (W + 151715840ULL);
  int*    tok_of = (int*)   (W + 151781376ULL);
  int*    slot_of= (int*)   (W + 151846912ULL);
  int*    counts = (int*)   (W + 151912448ULL);
  int*    cur    = counts + 8;
  int*    offs   = counts + 16;

  cvtT16<<<4096, 256, 0, stream>>>(wi0, w0Th, w0Tl, 512, 1024);
  cvtT16<<<4096, 256, 0, stream>>>(wi1, w1Th, w1Tl, 512, 1024);
  cvtT16<<<4096, 256, 0, stream>>>(wo,  woTh, woTl, 1024, 512);
  cvtT16<<<128,  256, 0, stream>>>(g1w, g1Th, g1Tl, 512, 256);

  for (int l = 0; l < 2; ++l){
    const float* xin = l ? (const float*)d_out : x0;
    ln_kernel<<<8192, 256, 0, stream>>>(xin, ln_g + l*512, ln_b + l*512, h);
    colstats<<<64, 256, 0, stream>>>(h, cs, cq);
    subj_kernel<<<8, 256, 0, stream>>>(sid, semb, h1w, h1b, h2w, h2b, s1w, s1b, s2w, s2b,
                                       cs, cq, a64, c64, l);
    hfcast<<<2048, 256, 0, stream>>>(h, a64, c64, hfh, hfl);
    zero_counts<<<1, 64, 0, stream>>>(counts);
    gate2_kernel<<<512, 256, 0, stream>>>(hfh, hfl, g1Th, g1Tl, g1b, g2w, g2b, idxa, warr, counts);
    offsets_kernel<<<1, 1, 0, stream>>>(counts, offs, cur);
    scatter_kernel<<<32, 256, 0, stream>>>(idxa, offs, cur, tok_of, slot_of);
    if (l == 0){
      up1_kernel<<<16384, 256, 0, stream>>>(hfh, hfl, w0Th, w0Tl, w1Th, w1Tl,
                                            tok_of, offs, counts, hid16h, hid16l);
      down1_kernel<<<8192, 256, 0, stream>>>(hid16h, hid16l, woTh, woTl, offs, counts, eo32);
    } else {
      uph_kernel<<<16384, 256, 0, stream>>>(hfh, w0Th, w1Th, tok_of, offs, counts, hid16h);
      dnh_kernel<<<8192, 256, 0, stream>>>(hid16h, woTh, offs, counts, eo32);
    }
    gather_kernel<<<8192, 128, 0, stream>>>(xin, eo32, slot_of, warr, (float*)d_out);
  }
}